// Round 30
// baseline (2699.262 us; speedup 1.0000x reference)
//
#include <hip/hip_runtime.h>
#include <hip/hip_fp16.h>
#include <cmath>

#define NN   50000
#define EE   800000
#define FF   64
#define HH   256
#define IDD  32
#define DYNN 16
#define BB   256
#define TT   128
#define DIN  304   /* HH + IDD + DYNN */
#define G3   768   /* 3*HH */
#define NQ   (HH/4)        /* 64 scan weight quads  */
#define NQG  ((FF+HH)/4)   /* 80 gnn weight quads   */
#define NQX  (DIN/4)       /* 76 xg weight quads    */

typedef _Float16 h2_t __attribute__((ext_vector_type(2)));
__device__ __forceinline__ float sigf(float x){ return 1.0f/(1.0f+expf(-x)); }
__device__ __forceinline__ float fdot2(__half2 a, __half2 b, float c) {
    return __builtin_amdgcn_fdot2(*reinterpret_cast<h2_t*>(&a),
                                  *reinterpret_cast<h2_t*>(&b), c, false);
}

/* ---------------- h = tanh(x0 @ Wproj + bproj)  (+ fp16 mirror) ---------------- */
#define NPB 16
__global__ __launch_bounds__(256) void k_proj(
    const float* __restrict__ x0, const float* __restrict__ Wproj,
    const float* __restrict__ bproj, float* __restrict__ h,
    __half* __restrict__ h16)
{
    __shared__ float xs[NPB][FF];
    int n0 = blockIdx.x * NPB;
    int j  = threadIdx.x;
    for (int i = j; i < NPB*FF; i += 256) {
        int m = i / FF, k = i % FF;
        int n = n0 + m;
        xs[m][k] = (n < NN) ? x0[n*FF + k] : 0.f;
    }
    __syncthreads();
    float acc[NPB];
#pragma unroll
    for (int m = 0; m < NPB; ++m) acc[m] = 0.f;
    for (int k = 0; k < FF; ++k) {
        float w = Wproj[k*HH + j];
#pragma unroll
        for (int m = 0; m < NPB; ++m) acc[m] += xs[m][k]*w;
    }
    float b = bproj[j];
#pragma unroll
    for (int m = 0; m < NPB; ++m) {
        int n = n0 + m;
        if (n < NN) {
            float v = tanhf(acc[m] + b);
            h[(size_t)n*HH + j] = v;
            h16[(size_t)n*HH + j] = __float2half(v);
        }
    }
}

/* ------- pack Wh (256x768) into quad-fp16: Wq[q*G3+j] = {Wh[4q..4q+3][j]} ------- */
__global__ __launch_bounds__(768) void k_wt2(
    const float* __restrict__ Wh, __half2* __restrict__ Wq)
{
    int q = blockIdx.x;          /* 0..63  */
    int j = threadIdx.x;         /* 0..767 */
    float w0 = Wh[(size_t)(4*q+0)*G3 + j];
    float w1 = Wh[(size_t)(4*q+1)*G3 + j];
    float w2 = Wh[(size_t)(4*q+2)*G3 + j];
    float w3 = Wh[(size_t)(4*q+3)*G3 + j];
    Wq[((size_t)q*G3 + j)*2 + 0] = __floats2half2_rn(w0, w1);
    Wq[((size_t)q*G3 + j)*2 + 1] = __floats2half2_rn(w2, w3);
}

/* ------- pack gnn W (320x256) into quad-fp16: Wq[q*HH+j] = {W[4q..4q+3][j]} ------- */
__global__ __launch_bounds__(256) void k_wtg(
    const float* __restrict__ W, float2* __restrict__ Wq)
{
    int q = blockIdx.x;          /* 0..79  */
    int j = threadIdx.x;         /* 0..255 */
    __half2 a = __floats2half2_rn(W[(size_t)(4*q+0)*HH + j], W[(size_t)(4*q+1)*HH + j]);
    __half2 b = __floats2half2_rn(W[(size_t)(4*q+2)*HH + j], W[(size_t)(4*q+3)*HH + j]);
    float2 o;
    reinterpret_cast<__half2*>(&o)[0] = a;
    reinterpret_cast<__half2*>(&o)[1] = b;
    Wq[(size_t)q*HH + j] = o;
}

/* ------- pack xg Wi (304x768) into quad-fp16: Wq[q*G3+j] = {Wi[4q..4q+3][j]} ------- */
__global__ __launch_bounds__(768) void k_wti(
    const float* __restrict__ Wi, float2* __restrict__ Wq)
{
    int q = blockIdx.x;          /* 0..75  */
    int j = threadIdx.x;         /* 0..767 */
    __half2 a = __floats2half2_rn(Wi[(size_t)(4*q+0)*G3 + j], Wi[(size_t)(4*q+1)*G3 + j]);
    __half2 b = __floats2half2_rn(Wi[(size_t)(4*q+2)*G3 + j], Wi[(size_t)(4*q+3)*G3 + j]);
    float2 o;
    reinterpret_cast<__half2*>(&o)[0] = a;
    reinterpret_cast<__half2*>(&o)[1] = b;
    Wq[(size_t)q*G3 + j] = o;
}

/* ---------------- CSR build: histogram / prefix / fill ---------------- */
__global__ __launch_bounds__(256) void k_hist(
    const int* __restrict__ dst, int* __restrict__ cnt)
{
    int e = blockIdx.x*256 + threadIdx.x;
    if (e < EE) atomicAdd(&cnt[dst[e]], 1);
}

__global__ __launch_bounds__(1024) void k_prefix(
    const int* __restrict__ cnt, int* __restrict__ offs)
{
    __shared__ int sm[1024];
    __shared__ int carry;
    int j = threadIdx.x;
    if (j == 0) carry = 0;
    __syncthreads();
    for (int base = 0; base < NN; base += 1024) {
        int v = (base + j < NN) ? cnt[base + j] : 0;
        sm[j] = v; __syncthreads();
        for (int s = 1; s < 1024; s <<= 1) {
            int t = (j >= s) ? sm[j - s] : 0;
            __syncthreads();
            sm[j] += t;
            __syncthreads();
        }
        int inc = sm[j];
        int c = carry;
        if (base + j < NN) offs[base + j] = c + inc - v;   /* exclusive */
        __syncthreads();
        if (j == 1023) carry = c + sm[1023];
        __syncthreads();
    }
    if (j == 0) offs[NN] = carry;
}

__global__ __launch_bounds__(256) void k_fill(
    const int* __restrict__ src, const int* __restrict__ dst,
    const int* __restrict__ offs, int* __restrict__ cur,
    int* __restrict__ srcb)
{
    int e = blockIdx.x*256 + threadIdx.x;
    if (e < EE) {
        int d = dst[e];
        int p = atomicAdd(&cur[d], 1);
        srcb[offs[d] + p] = src[e];
    }
}

/* ------- hagg[n] = sum over incoming edges of h16[src] (fp32 accumulate) -------
   2 edges per wave-pass: lanes 0-31 even edge, lanes 32-63 odd edge. */
#define APB 4   /* one wave per node, 4 nodes per block */
__global__ __launch_bounds__(256) void k_aggregate(
    const __half* __restrict__ h16, const int* __restrict__ offs,
    const int* __restrict__ srcb, float* __restrict__ hagg)
{
    int w    = threadIdx.x >> 6;
    int lane = threadIdx.x & 63;
    int half = lane >> 5;        /* 0: even edge, 1: odd edge   */
    int l32  = lane & 31;        /* covers cols l32*8 .. l32*8+7 */
    int n = blockIdx.x * APB + w;
    if (n >= NN) return;
    int e0 = offs[n], e1 = offs[n+1];
    float acc[8];
#pragma unroll
    for (int k = 0; k < 8; ++k) acc[k] = 0.f;
    int e = e0;
    for (; e + 8 <= e1; e += 8) {
        int sA = srcb[e     + half];
        int sB = srcb[e + 2 + half];
        int sC = srcb[e + 4 + half];
        int sD = srcb[e + 6 + half];
        float4 rA = *reinterpret_cast<const float4*>(&h16[(size_t)sA*HH + l32*8]);
        float4 rB = *reinterpret_cast<const float4*>(&h16[(size_t)sB*HH + l32*8]);
        float4 rC = *reinterpret_cast<const float4*>(&h16[(size_t)sC*HH + l32*8]);
        float4 rD = *reinterpret_cast<const float4*>(&h16[(size_t)sD*HH + l32*8]);
        const __half2* hA = reinterpret_cast<const __half2*>(&rA);
        const __half2* hB = reinterpret_cast<const __half2*>(&rB);
        const __half2* hC = reinterpret_cast<const __half2*>(&rC);
        const __half2* hD = reinterpret_cast<const __half2*>(&rD);
#pragma unroll
        for (int k = 0; k < 4; ++k) {
            float2 a = __half22float2(hA[k]);
            float2 b = __half22float2(hB[k]);
            float2 c = __half22float2(hC[k]);
            float2 d = __half22float2(hD[k]);
            acc[2*k]   += (a.x + b.x) + (c.x + d.x);
            acc[2*k+1] += (a.y + b.y) + (c.y + d.y);
        }
    }
    for (; e + 2 <= e1; e += 2) {
        int s = srcb[e + half];
        float4 r = *reinterpret_cast<const float4*>(&h16[(size_t)s*HH + l32*8]);
        const __half2* hp = reinterpret_cast<const __half2*>(&r);
#pragma unroll
        for (int k = 0; k < 4; ++k) {
            float2 a = __half22float2(hp[k]);
            acc[2*k] += a.x; acc[2*k+1] += a.y;
        }
    }
    if (e < e1 && half == 0) {   /* odd remainder: one edge, lanes 0-31 */
        int s = srcb[e];
        float4 r = *reinterpret_cast<const float4*>(&h16[(size_t)s*HH + l32*8]);
        const __half2* hp = reinterpret_cast<const __half2*>(&r);
#pragma unroll
        for (int k = 0; k < 4; ++k) {
            float2 a = __half22float2(hp[k]);
            acc[2*k] += a.x; acc[2*k+1] += a.y;
        }
    }
#pragma unroll
    for (int k = 0; k < 8; ++k) acc[k] += __shfl_xor(acc[k], 32, 64);
    if (half == 0) {
        float4 o0 = {acc[0], acc[1], acc[2], acc[3]};
        float4 o1 = {acc[4], acc[5], acc[6], acc[7]};
        float4* dst = reinterpret_cast<float4*>(&hagg[(size_t)n*HH + l32*8]);
        dst[0] = o0; dst[1] = o1;
    }
}

/* ------- h = (1-zg)*h_agg + zg*tanh([x0, rg*h_agg] @ Wn + bn), dot2-fp16 ------- */
__global__ __launch_bounds__(256) void k_gnn_update(
    const float* __restrict__ x0, const float* __restrict__ hagg,
    const float2* __restrict__ wqz, const float2* __restrict__ wqr,
    const float2* __restrict__ wqn,
    const float* __restrict__ bz, const float* __restrict__ br,
    const float* __restrict__ bn, float* __restrict__ h,
    __half* __restrict__ h16)
{
    __shared__ __align__(16) __half inh[NPB][FF+HH];  /* [x0(64) | hagg(256)] fp16 */
    __shared__ __align__(16) __half rhh[NPB][HH];     /* rg*hagg fp16 */
    __shared__ float hsf[NPB][HH];                    /* hagg fp32 (gate math) */
    int n0 = blockIdx.x * NPB;
    int j  = threadIdx.x;
    for (int i = j; i < NPB*FF; i += 256) {
        int m = i >> 6, k = i & 63;
        int n = n0 + m;
        inh[m][k] = __float2half((n < NN) ? x0[n*FF + k] : 0.f);
    }
#pragma unroll
    for (int m = 0; m < NPB; ++m) {
        int n = n0 + m;
        float hv = (n < NN) ? hagg[(size_t)n*HH + j] : 0.f;
        hsf[m][j] = hv;
        inh[m][FF + j] = __float2half(hv);
    }
    __syncthreads();

    float az[NPB], ar[NPB];
#pragma unroll
    for (int m = 0; m < NPB; ++m) { az[m] = 0.f; ar[m] = 0.f; }
    for (int q = 0; q < NQG; ++q) {
        float2 wzr = wqz[(size_t)q*HH + j];
        float2 wrr = wqr[(size_t)q*HH + j];
        __half2 wz01 = reinterpret_cast<__half2*>(&wzr)[0];
        __half2 wz23 = reinterpret_cast<__half2*>(&wzr)[1];
        __half2 wr01 = reinterpret_cast<__half2*>(&wrr)[0];
        __half2 wr23 = reinterpret_cast<__half2*>(&wrr)[1];
#pragma unroll
        for (int m = 0; m < NPB; ++m) {
            float2 hraw = *reinterpret_cast<const float2*>(&inh[m][4*q]);
            __half2 h01 = reinterpret_cast<__half2*>(&hraw)[0];
            __half2 h23 = reinterpret_cast<__half2*>(&hraw)[1];
            az[m] = fdot2(h01, wz01, az[m]); az[m] = fdot2(h23, wz23, az[m]);
            ar[m] = fdot2(h01, wr01, ar[m]); ar[m] = fdot2(h23, wr23, ar[m]);
        }
    }
    float bzj = bz[j], brj = br[j];
    float zg[NPB];
#pragma unroll
    for (int m = 0; m < NPB; ++m) {
        zg[m] = sigf(az[m] + bzj);
        float rg = sigf(ar[m] + brj);
        rhh[m][j] = __float2half(rg * hsf[m][j]);
    }
    __syncthreads();
    float an[NPB];
#pragma unroll
    for (int m = 0; m < NPB; ++m) an[m] = 0.f;
    /* x0 part: quads 0..15 read inh[m][4q] */
    for (int q = 0; q < FF/4; ++q) {
        float2 wnr = wqn[(size_t)q*HH + j];
        __half2 wn01 = reinterpret_cast<__half2*>(&wnr)[0];
        __half2 wn23 = reinterpret_cast<__half2*>(&wnr)[1];
#pragma unroll
        for (int m = 0; m < NPB; ++m) {
            float2 hraw = *reinterpret_cast<const float2*>(&inh[m][4*q]);
            __half2 h01 = reinterpret_cast<__half2*>(&hraw)[0];
            __half2 h23 = reinterpret_cast<__half2*>(&hraw)[1];
            an[m] = fdot2(h01, wn01, an[m]); an[m] = fdot2(h23, wn23, an[m]);
        }
    }
    /* r*h part: quads 16..79 read rhh[m][4q-64] */
    for (int q = FF/4; q < NQG; ++q) {
        float2 wnr = wqn[(size_t)q*HH + j];
        __half2 wn01 = reinterpret_cast<__half2*>(&wnr)[0];
        __half2 wn23 = reinterpret_cast<__half2*>(&wnr)[1];
#pragma unroll
        for (int m = 0; m < NPB; ++m) {
            float2 hraw = *reinterpret_cast<const float2*>(&rhh[m][4*q - FF]);
            __half2 h01 = reinterpret_cast<__half2*>(&hraw)[0];
            __half2 h23 = reinterpret_cast<__half2*>(&hraw)[1];
            an[m] = fdot2(h01, wn01, an[m]); an[m] = fdot2(h23, wn23, an[m]);
        }
    }
    float bnj = bn[j];
#pragma unroll
    for (int m = 0; m < NPB; ++m) {
        int n = n0 + m;
        if (n < NN) {
            float ht = tanhf(an[m] + bnj);
            float hv = (1.f - zg[m])*hsf[m][j] + zg[m]*ht;
            h[(size_t)n*HH + j] = hv;
            h16[(size_t)n*HH + j] = __float2half(hv);
        }
    }
}

/* ---------------- film = tanh((dyn@W1+b1)@W2+b2) ---------------- */
__global__ __launch_bounds__(256) void k_film(
    const float* __restrict__ dyn, const float* __restrict__ W1,
    const float* __restrict__ b1, const float* __restrict__ W2,
    const float* __restrict__ b2, float* __restrict__ film)
{
    __shared__ float t1[HH];
    __shared__ float ds[DYNN];
    int b = blockIdx.x, j = threadIdx.x;
    if (j < DYNN) ds[j] = dyn[b*DYNN + j];
    __syncthreads();
    float acc = b1[j];
    for (int k = 0; k < DYNN; ++k) acc += ds[k]*W1[k*HH + j];
    t1[j] = acc;                 /* inner layer is LINEAR in the reference */
    __syncthreads();
    float a0 = b2[j], a1 = b2[HH + j];
    for (int k = 0; k < HH; ++k) {
        float t = t1[k];
        a0 += t * W2[k*2*HH + j];
        a1 += t * W2[k*2*HH + HH + j];
    }
    film[b*2*HH + j]      = tanhf(a0);
    film[b*2*HH + HH + j] = tanhf(a1);
}

/* -- fused xg for BOTH directions, quad-fp16 dot2: dir = blockIdx.x / 2048 -- */
#define RPB 16
#define XGBLK ((BB*TT)/RPB)   /* 2048 blocks per direction */
__global__ __launch_bounds__(256) void k_xg2(
    const float* __restrict__ hfin, const float* __restrict__ id_emb,
    const float* __restrict__ dyn,  const float* __restrict__ film,
    const int* __restrict__ traj,   const int* __restrict__ lengths,
    const float2* __restrict__ Wqi_f, const float* __restrict__ bi_f,
    const float2* __restrict__ Wqi_b, const float* __restrict__ bi_b,
    __half* __restrict__ xg_f, __half* __restrict__ xg_b)
{
    __shared__ __align__(16) __half in[RPB][DIN];   /* fp16 inputs, 9728 B */
    int dir = blockIdx.x / XGBLK;          /* 0 = fwd, 1 = bwd */
    int r0  = (blockIdx.x - dir*XGBLK) * RPB;
    const float2* Wq = dir ? Wqi_b : Wqi_f;
    const float* bi = dir ? bi_b : bi_f;
    __half* xg = dir ? xg_b : xg_f;
    int j  = threadIdx.x;
#pragma unroll
    for (int m = 0; m < RPB; ++m) {
        int r = r0 + m;
        int b = r >> 7, t = r & 127;
        int tt = t;
        if (dir) { int L = lengths[b]; tt = L - 1 - t; if (tt < 0) tt = 0; }
        int idx = traj[b*TT + tt];
        float g  = film[b*2*HH + j];
        float bf = film[b*2*HH + HH + j];
        in[m][j] = __float2half(hfin[(size_t)idx*HH + j]*(1.f + g) + bf);
        if (j < IDD)               in[m][HH + j] = __float2half(id_emb[(size_t)idx*IDD + j]);
        else if (j < IDD + DYNN)   in[m][HH + IDD + (j - IDD)] = __float2half(dyn[b*DYNN + (j - IDD)]);
    }
    __syncthreads();
    float a0[RPB], a1[RPB], a2[RPB];
#pragma unroll
    for (int m = 0; m < RPB; ++m) { a0[m] = 0.f; a1[m] = 0.f; a2[m] = 0.f; }
    for (int q = 0; q < NQX; ++q) {
        float2 w0r = Wq[(size_t)q*G3 + j];
        float2 w1r = Wq[(size_t)q*G3 + HH + j];
        float2 w2r = Wq[(size_t)q*G3 + 2*HH + j];
        __half2 w0a = reinterpret_cast<__half2*>(&w0r)[0];
        __half2 w0b = reinterpret_cast<__half2*>(&w0r)[1];
        __half2 w1a = reinterpret_cast<__half2*>(&w1r)[0];
        __half2 w1b = reinterpret_cast<__half2*>(&w1r)[1];
        __half2 w2a = reinterpret_cast<__half2*>(&w2r)[0];
        __half2 w2b = reinterpret_cast<__half2*>(&w2r)[1];
#pragma unroll
        for (int m = 0; m < RPB; ++m) {
            float2 hraw = *reinterpret_cast<const float2*>(&in[m][4*q]);
            __half2 h01 = reinterpret_cast<__half2*>(&hraw)[0];
            __half2 h23 = reinterpret_cast<__half2*>(&hraw)[1];
            a0[m] = fdot2(h01, w0a, a0[m]); a0[m] = fdot2(h23, w0b, a0[m]);
            a1[m] = fdot2(h01, w1a, a1[m]); a1[m] = fdot2(h23, w1b, a1[m]);
            a2[m] = fdot2(h01, w2a, a2[m]); a2[m] = fdot2(h23, w2b, a2[m]);
        }
    }
    float bi0 = bi[j], bi1 = bi[HH + j], bi2 = bi[2*HH + j];
#pragma unroll
    for (int m = 0; m < RPB; ++m) {
        __half* o = &xg[(size_t)(r0 + m)*G3];
        o[j]        = __float2half(a0[m] + bi0);
        o[HH + j]   = __float2half(a1[m] + bi1);
        o[2*HH + j] = __float2half(a2[m] + bi2);
    }
}

/* -- masked GRU scan, NBS=4: 4 sequences per block, 64 blocks/direction.
   Per-step weight loads amortized over 4 matvecs (latency-bound model). -- */
#define NBS 4
#define SCBLK (BB/NBS)   /* 64 blocks per direction */
__global__ __launch_bounds__(768, 3) void k_scan2(
    const __half* __restrict__ xg_f, const __half* __restrict__ xg_b,
    const __half2* __restrict__ Wq_f, const float* __restrict__ bh_f,
    const __half2* __restrict__ Wq_b, const float* __restrict__ bh_b,
    const int* __restrict__ lengths,
    float* __restrict__ out_f, float* __restrict__ out_b,
    float* __restrict__ h_last)
{
    __shared__ float hsh[NBS][HH];                 /* fp32 master state   */
    __shared__ __align__(16) __half hshh[NBS][HH]; /* fp16 shadow (matvec)*/
    __shared__ float gh[NBS][G3];                  /* h @ Wh + bh         */
    int dir  = blockIdx.x / SCBLK;          /* 0 = fwd, 1 = bwd */
    int bblk = blockIdx.x - dir*SCBLK;
    const __half* xg = dir ? xg_b : xg_f;
    const __half2* Wq = dir ? Wq_b : Wq_f;
    const float* bh = dir ? bh_b : bh_f;
    float* out = dir ? out_b : out_f;
    int b0 = bblk * NBS;
    int j  = threadIdx.x;            /* 0..767 : output column */
    int jj = j & 255;
    int m0 = j >> 8;                 /* 0..2 ; gate threads have m0 in {0,1} */
    for (int i = j; i < NBS*HH; i += 768) {
        hsh[i >> 8][i & 255] = 0.f;
        hshh[i >> 8][i & 255] = __float2half(0.f);
    }
    int Ls[NBS];
#pragma unroll
    for (int s = 0; s < NBS; ++s) Ls[s] = lengths[b0 + s];
    float bhj = bh[j];
    const float2* wqp = reinterpret_cast<const float2*>(Wq) + j;
    __syncthreads();
    for (int t = 0; t < TT; ++t) {
        /* prefetch xg for the two sequences this thread gates (m0, m0+2) */
        float xr0 = 0.f, xz0 = 0.f, xn0 = 0.f;
        float xr1 = 0.f, xz1 = 0.f, xn1 = 0.f;
        if (j < 512) {
            const __half* xa = &xg[((size_t)(b0 + m0)*TT + t)*G3];
            const __half* xb = &xg[((size_t)(b0 + m0 + 2)*TT + t)*G3];
            xr0 = __half2float(xa[jj]);
            xz0 = __half2float(xa[HH + jj]);
            xn0 = __half2float(xa[2*HH + jj]);
            xr1 = __half2float(xb[jj]);
            xz1 = __half2float(xb[HH + jj]);
            xn1 = __half2float(xb[2*HH + jj]);
        }
        /* gh[s][j] = sum_k hshh[s][k]*W[k][j] + bh[j], 4 accumulators */
        float a0 = bhj, a1 = bhj, a2 = bhj, a3 = bhj;
#pragma unroll
        for (int p = 0; p < NQ/2; ++p) {
            float4 h0raw = *reinterpret_cast<const float4*>(&hshh[0][8*p]);
            float4 h1raw = *reinterpret_cast<const float4*>(&hshh[1][8*p]);
            float4 h2raw = *reinterpret_cast<const float4*>(&hshh[2][8*p]);
            float4 h3raw = *reinterpret_cast<const float4*>(&hshh[3][8*p]);
            const __half2* h0 = reinterpret_cast<const __half2*>(&h0raw);
            const __half2* h1 = reinterpret_cast<const __half2*>(&h1raw);
            const __half2* h2 = reinterpret_cast<const __half2*>(&h2raw);
            const __half2* h3 = reinterpret_cast<const __half2*>(&h3raw);
            float2 w0 = wqp[(size_t)(2*p)*G3], w1 = wqp[(size_t)(2*p+1)*G3];
            const __half2* wA = reinterpret_cast<const __half2*>(&w0);
            const __half2* wB = reinterpret_cast<const __half2*>(&w1);
            a0 = fdot2(h0[0], wA[0], a0); a0 = fdot2(h0[1], wA[1], a0);
            a0 = fdot2(h0[2], wB[0], a0); a0 = fdot2(h0[3], wB[1], a0);
            a1 = fdot2(h1[0], wA[0], a1); a1 = fdot2(h1[1], wA[1], a1);
            a1 = fdot2(h1[2], wB[0], a1); a1 = fdot2(h1[3], wB[1], a1);
            a2 = fdot2(h2[0], wA[0], a2); a2 = fdot2(h2[1], wA[1], a2);
            a2 = fdot2(h2[2], wB[0], a2); a2 = fdot2(h2[3], wB[1], a2);
            a3 = fdot2(h3[0], wA[0], a3); a3 = fdot2(h3[1], wA[1], a3);
            a3 = fdot2(h3[2], wB[0], a3); a3 = fdot2(h3[3], wB[1], a3);
        }
        gh[0][j] = a0; gh[1][j] = a1; gh[2][j] = a2; gh[3][j] = a3;
        __syncthreads();
        if (j < 512) {
#pragma unroll
            for (int ss = 0; ss < 2; ++ss) {
                int s = m0 + 2*ss;
                int b = b0 + s;
                int L = Ls[s];
                float xr = ss ? xr1 : xr0;
                float xz = ss ? xz1 : xz0;
                float xn = ss ? xn1 : xn0;
                float gr = sigf(xr + gh[s][jj]);
                float gz = sigf(xz + gh[s][HH + jj]);
                float gn = tanhf(xn + gr*gh[s][2*HH + jj]);
                float hold = hsh[s][jj];
                float hnew = (1.f - gz)*gn + gz*hold;
                if (t < L) {
                    hsh[s][jj] = hnew;
                    hshh[s][jj] = __float2half(hnew);
                    if (!dir) out[((size_t)b*TT + t)*HH + jj] = hnew;
                    else      out[((size_t)b*TT + (L-1-t))*HH + jj] = hnew;
                } else if (!dir) {
                    out[((size_t)b*TT + t)*HH + jj] = 0.f;
                }
            }
        }
        __syncthreads();
    }
    if (j < 512) {
#pragma unroll
        for (int ss = 0; ss < 2; ++ss) {
            int s = m0 + 2*ss;
            int b = b0 + s;
            int L = Ls[s];
            h_last[b*2*HH + (dir ? HH : 0) + jj] = hsh[s][jj];
            if (dir) {
                for (int t = L; t < TT; ++t) out[((size_t)b*TT + t)*HH + jj] = 0.f;
            }
        }
    }
}

/* ------- scores[b,t] = tanh([out_f|out_b|dyn] @ W1 + b1) @ W2 + b2, masked ------- */
#define SPB 16
#define SCD 528  /* 2*HH + DYNN */
__global__ __launch_bounds__(256) void k_scores(
    const float* __restrict__ out_f, const float* __restrict__ out_b,
    const float* __restrict__ dyn,   const int* __restrict__ traj,
    const float* __restrict__ W1,    const float* __restrict__ b1,
    const float* __restrict__ W2,    const float* __restrict__ b2,
    float* __restrict__ scores)
{
    __shared__ float in[SPB][SCD];
    __shared__ float part[4][SPB];
    int r0 = blockIdx.x * SPB;
    int j  = threadIdx.x;
    int lane = j & 63, wid = j >> 6;
#pragma unroll
    for (int m = 0; m < SPB; ++m) {
        int r = r0 + m;
        int b = r >> 7;
        in[m][j]      = out_f[(size_t)r*HH + j];
        in[m][HH + j] = out_b[(size_t)r*HH + j];
        if (j < DYNN) in[m][2*HH + j] = dyn[b*DYNN + j];
    }
    __syncthreads();
    float acc[SPB];
#pragma unroll
    for (int m = 0; m < SPB; ++m) acc[m] = 0.f;
    for (int k = 0; k < SCD; ++k) {
        float w = W1[k*HH + j];
#pragma unroll
        for (int m = 0; m < SPB; ++m) acc[m] += in[m][k]*w;
    }
    float b1j = b1[j], w2j = W2[j];
#pragma unroll
    for (int m = 0; m < SPB; ++m) {
        float s = tanhf(acc[m] + b1j) * w2j;
#pragma unroll
        for (int off = 32; off > 0; off >>= 1) s += __shfl_xor(s, off, 64);
        if (lane == 0) part[wid][m] = s;
    }
    __syncthreads();
    if (j < SPB) {
        int r = r0 + j;
        int b = r >> 7, t = r & 127;
        float s = part[0][j] + part[1][j] + part[2][j] + part[3][j];
        scores[r] = (traj[b*TT + t] != 0) ? (s + b2[0]) : -1e9f;
    }
}

/* ---------------- softmax over T + context = sum(alpha * rnn_out) ---------------- */
__global__ __launch_bounds__(256) void k_context(
    const float* __restrict__ scores, const float* __restrict__ out_f,
    const float* __restrict__ out_b,  float* __restrict__ context)
{
    __shared__ float al[TT];
    __shared__ float red[256];
    int b = blockIdx.x, j = threadIdx.x;
    float s = (j < TT) ? scores[b*TT + j] : -INFINITY;
    red[j] = s; __syncthreads();
    for (int t = 128; t > 0; t >>= 1) { if (j < t) red[j] = fmaxf(red[j], red[j+t]); __syncthreads(); }
    float mx = red[0]; __syncthreads();
    float e = (j < TT) ? expf(s - mx) : 0.f;
    red[j] = e; __syncthreads();
    for (int t = 128; t > 0; t >>= 1) { if (j < t) red[j] += red[j+t]; __syncthreads(); }
    float tot = red[0];
    if (j < TT) al[j] = e / tot;
    __syncthreads();
    float c0 = 0.f, c1 = 0.f;
    for (int t = 0; t < TT; ++t) {
        float a = al[t];
        c0 += a * out_f[((size_t)b*TT + t)*HH + j];
        c1 += a * out_b[((size_t)b*TT + t)*HH + j];
    }
    context[b*2*HH + j]      = c0;
    context[b*2*HH + HH + j] = c1;
}

/* ---------------- LayerNorm + gate + MLP head ---------------- */
__global__ __launch_bounds__(256) void k_head(
    const float* __restrict__ h_last, const float* __restrict__ context,
    const float* __restrict__ dyn,    const float* __restrict__ ln_g,
    const float* __restrict__ ln_b,   const float* __restrict__ gate_W,
    const float* __restrict__ gate_b, const float* __restrict__ fc_W1,
    const float* __restrict__ fc_b1,  const float* __restrict__ fc_W2,
    const float* __restrict__ fc_b2,  float* __restrict__ outp)
{
    __shared__ float gi[1040];   /* [context 512 | rnn_last 512 | dyn 16] */
    __shared__ float fin[SCD];   /* [final 512 | dyn 16] */
    __shared__ float red[256];
    int b = blockIdx.x, j = threadIdx.x;
    float h0 = h_last[b*2*HH + j], h1 = h_last[b*2*HH + HH + j];
    red[j] = h0 + h1; __syncthreads();
    for (int s = 128; s > 0; s >>= 1) { if (j < s) red[j] += red[j+s]; __syncthreads(); }
    float mu = red[0] / 512.f; __syncthreads();
    float d0 = h0 - mu, d1 = h1 - mu;
    red[j] = d0*d0 + d1*d1; __syncthreads();
    for (int s = 128; s > 0; s >>= 1) { if (j < s) red[j] += red[j+s]; __syncthreads(); }
    float inv = rsqrtf(red[0] / 512.f + 1e-5f); __syncthreads();
    gi[2*HH + j]      = d0*inv*ln_g[j]      + ln_b[j];
    gi[2*HH + HH + j] = d1*inv*ln_g[HH + j] + ln_b[HH + j];
    gi[j]      = context[b*2*HH + j];
    gi[HH + j] = context[b*2*HH + HH + j];
    if (j < DYNN) gi[1024 + j] = dyn[b*DYNN + j];
    __syncthreads();
    float a0 = gate_b[j], a1 = gate_b[HH + j];
    for (int k = 0; k < 1040; ++k) {
        float x = gi[k];
        a0 += x * gate_W[k*2*HH + j];
        a1 += x * gate_W[k*2*HH + HH + j];
    }
    float z0 = sigf(a0), z1 = sigf(a1);
    fin[j]      = z0*gi[j]      + (1.f - z0)*gi[2*HH + j];
    fin[HH + j] = z1*gi[HH + j] + (1.f - z1)*gi[2*HH + HH + j];
    if (j < DYNN) fin[2*HH + j] = gi[1024 + j];
    __syncthreads();
    float acc = fc_b1[j];
    for (int k = 0; k < SCD; ++k) acc += fin[k]*fc_W1[k*HH + j];
    float x = acc;
    float hfc = 0.5f * x * (1.f + erff(x * 0.70710678118654752f));  /* exact GELU */
    red[j] = hfc * fc_W2[j]; __syncthreads();
    for (int s = 128; s > 0; s >>= 1) { if (j < s) red[j] += red[j+s]; __syncthreads(); }
    if (j == 0) outp[b] = red[0] + fc_b2[0];
}

extern "C" void kernel_launch(void* const* d_in, const int* in_sizes, int n_in,
                              void* d_out, int out_size, void* d_ws, size_t ws_size,
                              hipStream_t stream)
{
    const float* x0      = (const float*)d_in[0];
    const float* dyn     = (const float*)d_in[1];
    const float* Wproj   = (const float*)d_in[2];
    const float* bproj   = (const float*)d_in[3];
    const float* Wz      = (const float*)d_in[4];
    const float* bz      = (const float*)d_in[5];
    const float* Wr      = (const float*)d_in[6];
    const float* br      = (const float*)d_in[7];
    const float* Wn      = (const float*)d_in[8];
    const float* bn      = (const float*)d_in[9];
    const float* id_emb  = (const float*)d_in[10];
    const float* film_W1 = (const float*)d_in[11];
    const float* film_b1 = (const float*)d_in[12];
    const float* film_W2 = (const float*)d_in[13];
    const float* film_b2 = (const float*)d_in[14];
    const float* gWi_f   = (const float*)d_in[15];
    const float* gWh_f   = (const float*)d_in[16];
    const float* gbi_f   = (const float*)d_in[17];
    const float* gbh_f   = (const float*)d_in[18];
    const float* gWi_b   = (const float*)d_in[19];
    const float* gWh_b   = (const float*)d_in[20];
    const float* gbi_b   = (const float*)d_in[21];
    const float* gbh_b   = (const float*)d_in[22];
    const float* ln_g    = (const float*)d_in[23];
    const float* ln_b    = (const float*)d_in[24];
    const float* attn_W1 = (const float*)d_in[25];
    const float* attn_b1 = (const float*)d_in[26];
    const float* attn_W2 = (const float*)d_in[27];
    const float* attn_b2 = (const float*)d_in[28];
    const float* gate_W  = (const float*)d_in[29];
    const float* gate_b  = (const float*)d_in[30];
    const float* fc_W1   = (const float*)d_in[31];
    const float* fc_b1   = (const float*)d_in[32];
    const float* fc_W2   = (const float*)d_in[33];
    const float* fc_b2   = (const float*)d_in[34];
    const int*   traj    = (const int*)d_in[35];
    const int*   lengths = (const int*)d_in[36];
    const int*   e_src   = (const int*)d_in[37];
    const int*   e_dst   = (const int*)d_in[38];

    float* ws = (float*)d_ws;
    const size_t off_h      = 0;
    const size_t off_hagg   = (size_t)NN*HH;                     /* 12,800,000 */
    const size_t off_xgf    = off_hagg;
    const size_t off_xgb    = off_xgf + (size_t)BB*TT*G3/2;
    const size_t off_outf   = 0;
    const size_t off_outb   = off_xgb + (size_t)BB*TT*G3/2;      /* 37,965,824 */
    const size_t off_film   = off_outb + (size_t)BB*TT*HH;       /* 46,354,432 */
    const size_t off_hlast  = off_film + (size_t)BB*2*HH;
    const size_t off_scores = off_hlast + (size_t)BB*2*HH;
    const size_t off_ctx    = off_scores + (size_t)BB*TT;
    const size_t off_wqf    = off_ctx + (size_t)BB*2*HH;
    const size_t off_wqb    = off_wqf + (size_t)NQ*G3*2;         /* 98,304 floats each */
    const size_t off_wqz    = off_wqb + (size_t)NQ*G3*2;
    const size_t off_wqr    = off_wqz + (size_t)NQG*HH*2;        /* 40,960 floats each */
    const size_t off_wqn    = off_wqr + (size_t)NQG*HH*2;
    const size_t off_wif    = off_wqn + (size_t)NQG*HH*2;        /* 116,736 floats each */
    const size_t off_wib    = off_wif + (size_t)NQX*G3*2;
    const size_t off_h16    = 27000000;                          /* inside dead xg_b region */

    float*   h      = ws + off_h;
    float*   hagg   = ws + off_hagg;
    __half*  xg_f   = (__half*)(ws + off_xgf);
    __half*  xg_b   = (__half*)(ws + off_xgb);
    float*   out_f  = ws + off_outf;
    float*   out_b  = ws + off_outb;
    float*   film   = ws + off_film;
    float*   hlast  = ws + off_hlast;
    float*   scores = ws + off_scores;
    float*   ctx    = ws + off_ctx;
    __half2* wq_f   = (__half2*)(ws + off_wqf);
    __half2* wq_b   = (__half2*)(ws + off_wqb);
    float2*  wqz    = (float2*)(ws + off_wqz);
    float2*  wqr    = (float2*)(ws + off_wqr);
    float2*  wqn    = (float2*)(ws + off_wqn);
    float2*  wqi_f  = (float2*)(ws + off_wif);
    float2*  wqi_b  = (float2*)(ws + off_wib);
    __half*  h16    = (__half*)(ws + off_h16);

    /* CSR scratch lives after hagg, inside the xg region (dead after GNN) */
    int* cnt  = (int*)(ws + off_hagg + (size_t)NN*HH);  /* [NN]   */
    int* cur  = cnt + NN;                               /* [NN]   */
    int* offs = cur + NN;                               /* [NN+1] */
    int* srcb = offs + NN + 1;                          /* [EE]   */

    /* ---- GNN ---- */
    k_proj<<<(NN + NPB - 1)/NPB, 256, 0, stream>>>(x0, Wproj, bproj, h, h16);

    /* pack weights once per call */
    k_wt2<<<NQ, 768, 0, stream>>>(gWh_f, wq_f);
    k_wt2<<<NQ, 768, 0, stream>>>(gWh_b, wq_b);
    k_wtg<<<NQG, 256, 0, stream>>>(Wz, wqz);
    k_wtg<<<NQG, 256, 0, stream>>>(Wr, wqr);
    k_wtg<<<NQG, 256, 0, stream>>>(Wn, wqn);
    k_wti<<<NQX, 768, 0, stream>>>(gWi_f, wqi_f);
    k_wti<<<NQX, 768, 0, stream>>>(gWi_b, wqi_b);

    /* build CSR once per call (graph static across the 3 steps) */
    hipMemsetAsync(cnt, 0, 2*(size_t)NN*sizeof(int), stream);   /* cnt + cur */
    k_hist<<<(EE + 255)/256, 256, 0, stream>>>(e_dst, cnt);
    k_prefix<<<1, 1024, 0, stream>>>(cnt, offs);
    k_fill<<<(EE + 255)/256, 256, 0, stream>>>(e_src, e_dst, offs, cur, srcb);

    for (int step = 0; step < 3; ++step) {
        k_aggregate<<<(NN + APB - 1)/APB, 256, 0, stream>>>(h16, offs, srcb, hagg);
        k_gnn_update<<<(NN + NPB - 1)/NPB, 256, 0, stream>>>(
            x0, hagg, wqz, wqr, wqn, bz, br, bn, h, h16);
    }

    /* ---- FiLM ---- */
    k_film<<<BB, 256, 0, stream>>>(dyn, film_W1, film_b1, film_W2, film_b2, film);

    /* ---- fused xg (both directions, quad-fp16 dot2) ---- */
    k_xg2<<<2*XGBLK, 256, 0, stream>>>(h, id_emb, dyn, film, traj, lengths,
                                       wqi_f, gbi_f, wqi_b, gbi_b, xg_f, xg_b);

    /* ---- GRU scan: NBS=4, 128 blocks total ---- */
    k_scan2<<<2*SCBLK, 768, 0, stream>>>(xg_f, xg_b, wq_f, gbh_f, wq_b, gbh_b,
                                         lengths, out_f, out_b, hlast);

    /* ---- attention + head ---- */
    k_scores<<<(BB*TT)/SPB, 256, 0, stream>>>(out_f, out_b, dyn, traj,
                                              attn_W1, attn_b1, attn_W2, attn_b2, scores);
    k_context<<<BB, 256, 0, stream>>>(scores, out_f, out_b, ctx);
    k_head<<<BB, 256, 0, stream>>>(hlast, ctx, dyn, ln_g, ln_b, gate_W, gate_b,
                                   fc_W1, fc_b1, fc_W2, fc_b2, (float*)d_out);
}

// Round 31
// 2215.107 us; speedup vs baseline: 1.2186x; 1.2186x over previous
//
#include <hip/hip_runtime.h>
#include <hip/hip_fp16.h>
#include <cmath>

#define NN   50000
#define EE   800000
#define FF   64
#define HH   256
#define IDD  32
#define DYNN 16
#define BB   256
#define TT   128
#define DIN  304   /* HH + IDD + DYNN */
#define G3   768   /* 3*HH */
#define NQ   (HH/4)        /* 64 scan weight quads  */
#define NQG  ((FF+HH)/4)   /* 80 gnn weight quads   */
#define NQX  (DIN/4)       /* 76 xg weight quads    */

typedef _Float16 h2_t __attribute__((ext_vector_type(2)));
__device__ __forceinline__ float sigf(float x){ return 1.0f/(1.0f+expf(-x)); }
__device__ __forceinline__ float fdot2(__half2 a, __half2 b, float c) {
    return __builtin_amdgcn_fdot2(*reinterpret_cast<h2_t*>(&a),
                                  *reinterpret_cast<h2_t*>(&b), c, false);
}

/* ---------------- h = tanh(x0 @ Wproj + bproj)  (+ fp16 mirror) ---------------- */
#define NPB 16
__global__ __launch_bounds__(256) void k_proj(
    const float* __restrict__ x0, const float* __restrict__ Wproj,
    const float* __restrict__ bproj, float* __restrict__ h,
    __half* __restrict__ h16)
{
    __shared__ float xs[NPB][FF];
    int n0 = blockIdx.x * NPB;
    int j  = threadIdx.x;
    for (int i = j; i < NPB*FF; i += 256) {
        int m = i / FF, k = i % FF;
        int n = n0 + m;
        xs[m][k] = (n < NN) ? x0[n*FF + k] : 0.f;
    }
    __syncthreads();
    float acc[NPB];
#pragma unroll
    for (int m = 0; m < NPB; ++m) acc[m] = 0.f;
    for (int k = 0; k < FF; ++k) {
        float w = Wproj[k*HH + j];
#pragma unroll
        for (int m = 0; m < NPB; ++m) acc[m] += xs[m][k]*w;
    }
    float b = bproj[j];
#pragma unroll
    for (int m = 0; m < NPB; ++m) {
        int n = n0 + m;
        if (n < NN) {
            float v = tanhf(acc[m] + b);
            h[(size_t)n*HH + j] = v;
            h16[(size_t)n*HH + j] = __float2half(v);
        }
    }
}

/* ------- pack Wh (256x768) into quad-fp16: Wq[q*G3+j] = {Wh[4q..4q+3][j]} ------- */
__global__ __launch_bounds__(768) void k_wt2(
    const float* __restrict__ Wh, __half2* __restrict__ Wq)
{
    int q = blockIdx.x;          /* 0..63  */
    int j = threadIdx.x;         /* 0..767 */
    float w0 = Wh[(size_t)(4*q+0)*G3 + j];
    float w1 = Wh[(size_t)(4*q+1)*G3 + j];
    float w2 = Wh[(size_t)(4*q+2)*G3 + j];
    float w3 = Wh[(size_t)(4*q+3)*G3 + j];
    Wq[((size_t)q*G3 + j)*2 + 0] = __floats2half2_rn(w0, w1);
    Wq[((size_t)q*G3 + j)*2 + 1] = __floats2half2_rn(w2, w3);
}

/* ------- pack [R x 256] into quad-fp16: Wq[q*HH+j] = {W[4q..4q+3][j]} ------- */
__global__ __launch_bounds__(256) void k_wtg(
    const float* __restrict__ W, float2* __restrict__ Wq)
{
    int q = blockIdx.x;
    int j = threadIdx.x;         /* 0..255 */
    __half2 a = __floats2half2_rn(W[(size_t)(4*q+0)*HH + j], W[(size_t)(4*q+1)*HH + j]);
    __half2 b = __floats2half2_rn(W[(size_t)(4*q+2)*HH + j], W[(size_t)(4*q+3)*HH + j]);
    float2 o;
    reinterpret_cast<__half2*>(&o)[0] = a;
    reinterpret_cast<__half2*>(&o)[1] = b;
    Wq[(size_t)q*HH + j] = o;
}

/* ------- pack xg Wi (304x768) into quad-fp16: Wq[q*G3+j] = {Wi[4q..4q+3][j]} ------- */
__global__ __launch_bounds__(768) void k_wti(
    const float* __restrict__ Wi, float2* __restrict__ Wq)
{
    int q = blockIdx.x;          /* 0..75  */
    int j = threadIdx.x;         /* 0..767 */
    __half2 a = __floats2half2_rn(Wi[(size_t)(4*q+0)*G3 + j], Wi[(size_t)(4*q+1)*G3 + j]);
    __half2 b = __floats2half2_rn(Wi[(size_t)(4*q+2)*G3 + j], Wi[(size_t)(4*q+3)*G3 + j]);
    float2 o;
    reinterpret_cast<__half2*>(&o)[0] = a;
    reinterpret_cast<__half2*>(&o)[1] = b;
    Wq[(size_t)q*G3 + j] = o;
}

/* ---------------- CSR build: histogram / prefix / fill ---------------- */
__global__ __launch_bounds__(256) void k_hist(
    const int* __restrict__ dst, int* __restrict__ cnt)
{
    int e = blockIdx.x*256 + threadIdx.x;
    if (e < EE) atomicAdd(&cnt[dst[e]], 1);
}

__global__ __launch_bounds__(1024) void k_prefix(
    const int* __restrict__ cnt, int* __restrict__ offs)
{
    __shared__ int sm[1024];
    __shared__ int carry;
    int j = threadIdx.x;
    if (j == 0) carry = 0;
    __syncthreads();
    for (int base = 0; base < NN; base += 1024) {
        int v = (base + j < NN) ? cnt[base + j] : 0;
        sm[j] = v; __syncthreads();
        for (int s = 1; s < 1024; s <<= 1) {
            int t = (j >= s) ? sm[j - s] : 0;
            __syncthreads();
            sm[j] += t;
            __syncthreads();
        }
        int inc = sm[j];
        int c = carry;
        if (base + j < NN) offs[base + j] = c + inc - v;   /* exclusive */
        __syncthreads();
        if (j == 1023) carry = c + sm[1023];
        __syncthreads();
    }
    if (j == 0) offs[NN] = carry;
}

__global__ __launch_bounds__(256) void k_fill(
    const int* __restrict__ src, const int* __restrict__ dst,
    const int* __restrict__ offs, int* __restrict__ cur,
    int* __restrict__ srcb)
{
    int e = blockIdx.x*256 + threadIdx.x;
    if (e < EE) {
        int d = dst[e];
        int p = atomicAdd(&cur[d], 1);
        srcb[offs[d] + p] = src[e];
    }
}

/* ------- hagg[n] = sum over incoming edges of h16[src] (fp32 accumulate) ------- */
#define APB 4   /* one wave per node, 4 nodes per block */
__global__ __launch_bounds__(256) void k_aggregate(
    const __half* __restrict__ h16, const int* __restrict__ offs,
    const int* __restrict__ srcb, float* __restrict__ hagg)
{
    int w    = threadIdx.x >> 6;
    int lane = threadIdx.x & 63;
    int n = blockIdx.x * APB + w;
    if (n >= NN) return;
    int e0 = offs[n], e1 = offs[n+1];
    float4 acc = {0.f, 0.f, 0.f, 0.f};
    int e = e0;
    for (; e + 4 <= e1; e += 4) {
        int s0 = srcb[e], s1 = srcb[e+1], s2 = srcb[e+2], s3 = srcb[e+3];
        float2 r0 = *reinterpret_cast<const float2*>(&h16[(size_t)s0*HH + lane*4]);
        float2 r1 = *reinterpret_cast<const float2*>(&h16[(size_t)s1*HH + lane*4]);
        float2 r2 = *reinterpret_cast<const float2*>(&h16[(size_t)s2*HH + lane*4]);
        float2 r3 = *reinterpret_cast<const float2*>(&h16[(size_t)s3*HH + lane*4]);
#pragma unroll
        for (int u = 0; u < 4; ++u) {
            float2* rp = (u==0)?&r0:(u==1)?&r1:(u==2)?&r2:&r3;
            float2 a = __half22float2(reinterpret_cast<__half2*>(rp)[0]);
            float2 b = __half22float2(reinterpret_cast<__half2*>(rp)[1]);
            acc.x += a.x; acc.y += a.y; acc.z += b.x; acc.w += b.y;
        }
    }
    for (; e < e1; ++e) {
        int s = srcb[e];
        float2 r = *reinterpret_cast<const float2*>(&h16[(size_t)s*HH + lane*4]);
        float2 a = __half22float2(reinterpret_cast<__half2*>(&r)[0]);
        float2 b = __half22float2(reinterpret_cast<__half2*>(&r)[1]);
        acc.x += a.x; acc.y += a.y; acc.z += b.x; acc.w += b.y;
    }
    *reinterpret_cast<float4*>(&hagg[(size_t)n*HH + lane*4]) = acc;
}

/* ------- h = (1-zg)*h_agg + zg*tanh([x0, rg*h_agg] @ Wn + bn), dot2-fp16 ------- */
__global__ __launch_bounds__(256) void k_gnn_update(
    const float* __restrict__ x0, const float* __restrict__ hagg,
    const float2* __restrict__ wqz, const float2* __restrict__ wqr,
    const float2* __restrict__ wqn,
    const float* __restrict__ bz, const float* __restrict__ br,
    const float* __restrict__ bn, float* __restrict__ h,
    __half* __restrict__ h16)
{
    __shared__ __align__(16) __half inh[NPB][FF+HH];  /* [x0(64) | hagg(256)] fp16 */
    __shared__ __align__(16) __half rhh[NPB][HH];     /* rg*hagg fp16 */
    __shared__ float hsf[NPB][HH];                    /* hagg fp32 (gate math) */
    int n0 = blockIdx.x * NPB;
    int j  = threadIdx.x;
    for (int i = j; i < NPB*FF; i += 256) {
        int m = i >> 6, k = i & 63;
        int n = n0 + m;
        inh[m][k] = __float2half((n < NN) ? x0[n*FF + k] : 0.f);
    }
#pragma unroll
    for (int m = 0; m < NPB; ++m) {
        int n = n0 + m;
        float hv = (n < NN) ? hagg[(size_t)n*HH + j] : 0.f;
        hsf[m][j] = hv;
        inh[m][FF + j] = __float2half(hv);
    }
    __syncthreads();

    float az[NPB], ar[NPB];
#pragma unroll
    for (int m = 0; m < NPB; ++m) { az[m] = 0.f; ar[m] = 0.f; }
    for (int q = 0; q < NQG; ++q) {
        float2 wzr = wqz[(size_t)q*HH + j];
        float2 wrr = wqr[(size_t)q*HH + j];
        __half2 wz01 = reinterpret_cast<__half2*>(&wzr)[0];
        __half2 wz23 = reinterpret_cast<__half2*>(&wzr)[1];
        __half2 wr01 = reinterpret_cast<__half2*>(&wrr)[0];
        __half2 wr23 = reinterpret_cast<__half2*>(&wrr)[1];
#pragma unroll
        for (int m = 0; m < NPB; ++m) {
            float2 hraw = *reinterpret_cast<const float2*>(&inh[m][4*q]);
            __half2 h01 = reinterpret_cast<__half2*>(&hraw)[0];
            __half2 h23 = reinterpret_cast<__half2*>(&hraw)[1];
            az[m] = fdot2(h01, wz01, az[m]); az[m] = fdot2(h23, wz23, az[m]);
            ar[m] = fdot2(h01, wr01, ar[m]); ar[m] = fdot2(h23, wr23, ar[m]);
        }
    }
    float bzj = bz[j], brj = br[j];
    float zg[NPB];
#pragma unroll
    for (int m = 0; m < NPB; ++m) {
        zg[m] = sigf(az[m] + bzj);
        float rg = sigf(ar[m] + brj);
        rhh[m][j] = __float2half(rg * hsf[m][j]);
    }
    __syncthreads();
    float an[NPB];
#pragma unroll
    for (int m = 0; m < NPB; ++m) an[m] = 0.f;
    /* x0 part: quads 0..15 read inh[m][4q] */
    for (int q = 0; q < FF/4; ++q) {
        float2 wnr = wqn[(size_t)q*HH + j];
        __half2 wn01 = reinterpret_cast<__half2*>(&wnr)[0];
        __half2 wn23 = reinterpret_cast<__half2*>(&wnr)[1];
#pragma unroll
        for (int m = 0; m < NPB; ++m) {
            float2 hraw = *reinterpret_cast<const float2*>(&inh[m][4*q]);
            __half2 h01 = reinterpret_cast<__half2*>(&hraw)[0];
            __half2 h23 = reinterpret_cast<__half2*>(&hraw)[1];
            an[m] = fdot2(h01, wn01, an[m]); an[m] = fdot2(h23, wn23, an[m]);
        }
    }
    /* r*h part: quads 16..79 read rhh[m][4q-64] */
    for (int q = FF/4; q < NQG; ++q) {
        float2 wnr = wqn[(size_t)q*HH + j];
        __half2 wn01 = reinterpret_cast<__half2*>(&wnr)[0];
        __half2 wn23 = reinterpret_cast<__half2*>(&wnr)[1];
#pragma unroll
        for (int m = 0; m < NPB; ++m) {
            float2 hraw = *reinterpret_cast<const float2*>(&rhh[m][4*q - FF]);
            __half2 h01 = reinterpret_cast<__half2*>(&hraw)[0];
            __half2 h23 = reinterpret_cast<__half2*>(&hraw)[1];
            an[m] = fdot2(h01, wn01, an[m]); an[m] = fdot2(h23, wn23, an[m]);
        }
    }
    float bnj = bn[j];
#pragma unroll
    for (int m = 0; m < NPB; ++m) {
        int n = n0 + m;
        if (n < NN) {
            float ht = tanhf(an[m] + bnj);
            float hv = (1.f - zg[m])*hsf[m][j] + zg[m]*ht;
            h[(size_t)n*HH + j] = hv;
            h16[(size_t)n*HH + j] = __float2half(hv);
        }
    }
}

/* ---------------- film = tanh((dyn@W1+b1)@W2+b2) ---------------- */
__global__ __launch_bounds__(256) void k_film(
    const float* __restrict__ dyn, const float* __restrict__ W1,
    const float* __restrict__ b1, const float* __restrict__ W2,
    const float* __restrict__ b2, float* __restrict__ film)
{
    __shared__ float t1[HH];
    __shared__ float ds[DYNN];
    int b = blockIdx.x, j = threadIdx.x;
    if (j < DYNN) ds[j] = dyn[b*DYNN + j];
    __syncthreads();
    float acc = b1[j];
    for (int k = 0; k < DYNN; ++k) acc += ds[k]*W1[k*HH + j];
    t1[j] = acc;                 /* inner layer is LINEAR in the reference */
    __syncthreads();
    float a0 = b2[j], a1 = b2[HH + j];
    for (int k = 0; k < HH; ++k) {
        float t = t1[k];
        a0 += t * W2[k*2*HH + j];
        a1 += t * W2[k*2*HH + HH + j];
    }
    film[b*2*HH + j]      = tanhf(a0);
    film[b*2*HH + HH + j] = tanhf(a1);
}

/* -- fused xg for BOTH directions, quad-fp16 dot2: dir = blockIdx.x / 2048 -- */
#define RPB 16
#define XGBLK ((BB*TT)/RPB)   /* 2048 blocks per direction */
__global__ __launch_bounds__(256) void k_xg2(
    const float* __restrict__ hfin, const float* __restrict__ id_emb,
    const float* __restrict__ dyn,  const float* __restrict__ film,
    const int* __restrict__ traj,   const int* __restrict__ lengths,
    const float2* __restrict__ Wqi_f, const float* __restrict__ bi_f,
    const float2* __restrict__ Wqi_b, const float* __restrict__ bi_b,
    __half* __restrict__ xg_f, __half* __restrict__ xg_b)
{
    __shared__ __align__(16) __half in[RPB][DIN];   /* fp16 inputs, 9728 B */
    int dir = blockIdx.x / XGBLK;          /* 0 = fwd, 1 = bwd */
    int r0  = (blockIdx.x - dir*XGBLK) * RPB;
    const float2* Wq = dir ? Wqi_b : Wqi_f;
    const float* bi = dir ? bi_b : bi_f;
    __half* xg = dir ? xg_b : xg_f;
    int j  = threadIdx.x;
#pragma unroll
    for (int m = 0; m < RPB; ++m) {
        int r = r0 + m;
        int b = r >> 7, t = r & 127;
        int tt = t;
        if (dir) { int L = lengths[b]; tt = L - 1 - t; if (tt < 0) tt = 0; }
        int idx = traj[b*TT + tt];
        float g  = film[b*2*HH + j];
        float bf = film[b*2*HH + HH + j];
        in[m][j] = __float2half(hfin[(size_t)idx*HH + j]*(1.f + g) + bf);
        if (j < IDD)               in[m][HH + j] = __float2half(id_emb[(size_t)idx*IDD + j]);
        else if (j < IDD + DYNN)   in[m][HH + IDD + (j - IDD)] = __float2half(dyn[b*DYNN + (j - IDD)]);
    }
    __syncthreads();
    float a0[RPB], a1[RPB], a2[RPB];
#pragma unroll
    for (int m = 0; m < RPB; ++m) { a0[m] = 0.f; a1[m] = 0.f; a2[m] = 0.f; }
    for (int q = 0; q < NQX; ++q) {
        float2 w0r = Wq[(size_t)q*G3 + j];
        float2 w1r = Wq[(size_t)q*G3 + HH + j];
        float2 w2r = Wq[(size_t)q*G3 + 2*HH + j];
        __half2 w0a = reinterpret_cast<__half2*>(&w0r)[0];
        __half2 w0b = reinterpret_cast<__half2*>(&w0r)[1];
        __half2 w1a = reinterpret_cast<__half2*>(&w1r)[0];
        __half2 w1b = reinterpret_cast<__half2*>(&w1r)[1];
        __half2 w2a = reinterpret_cast<__half2*>(&w2r)[0];
        __half2 w2b = reinterpret_cast<__half2*>(&w2r)[1];
#pragma unroll
        for (int m = 0; m < RPB; ++m) {
            float2 hraw = *reinterpret_cast<const float2*>(&in[m][4*q]);
            __half2 h01 = reinterpret_cast<__half2*>(&hraw)[0];
            __half2 h23 = reinterpret_cast<__half2*>(&hraw)[1];
            a0[m] = fdot2(h01, w0a, a0[m]); a0[m] = fdot2(h23, w0b, a0[m]);
            a1[m] = fdot2(h01, w1a, a1[m]); a1[m] = fdot2(h23, w1b, a1[m]);
            a2[m] = fdot2(h01, w2a, a2[m]); a2[m] = fdot2(h23, w2b, a2[m]);
        }
    }
    float bi0 = bi[j], bi1 = bi[HH + j], bi2 = bi[2*HH + j];
#pragma unroll
    for (int m = 0; m < RPB; ++m) {
        __half* o = &xg[(size_t)(r0 + m)*G3];
        o[j]        = __float2half(a0[m] + bi0);
        o[HH + j]   = __float2half(a1[m] + bi1);
        o[2*HH + j] = __float2half(a2[m] + bi2);
    }
}

/* -- fused masked GRU scan: NBS=2, dot2 fp16 (proven best structure) -- */
#define NBS 2
#define SCBLK (BB/NBS)   /* 128 blocks per direction */
__global__ __launch_bounds__(768, 3) void k_scan2(
    const __half* __restrict__ xg_f, const __half* __restrict__ xg_b,
    const __half2* __restrict__ Wq_f, const float* __restrict__ bh_f,
    const __half2* __restrict__ Wq_b, const float* __restrict__ bh_b,
    const int* __restrict__ lengths,
    float* __restrict__ out_f, float* __restrict__ out_b,
    float* __restrict__ h_last)
{
    __shared__ float hsh[NBS][HH];                 /* fp32 master state   */
    __shared__ __align__(16) __half hshh[NBS][HH]; /* fp16 shadow (matvec)*/
    __shared__ float gh[NBS][G3];                  /* h @ Wh + bh         */
    int dir  = blockIdx.x / SCBLK;          /* 0 = fwd, 1 = bwd */
    int bblk = blockIdx.x - dir*SCBLK;
    const __half* xg = dir ? xg_b : xg_f;
    const __half2* Wq = dir ? Wq_b : Wq_f;
    const float* bh = dir ? bh_b : bh_f;
    float* out = dir ? out_b : out_f;
    int b0 = bblk * NBS;
    int j  = threadIdx.x;            /* 0..767 : output column */
    int m  = j >> 8;                 /* valid when j<512 */
    int jj = j & 255;
    if (j < NBS*HH) { hsh[j >> 8][j & 255] = 0.f; hshh[j >> 8][j & 255] = __float2half(0.f); }
    int L0 = lengths[b0], L1 = lengths[b0 + 1];
    float bhj = bh[j];
    const float2* wqp = reinterpret_cast<const float2*>(Wq) + j;
    float2 wreg[NQ];
#pragma unroll
    for (int q = 0; q < NQ; ++q) wreg[q] = wqp[(size_t)q*G3];
    __syncthreads();
    for (int t = 0; t < TT; ++t) {
        /* prefetch my xg entries for this step (hidden under the matvec) */
        float xrv = 0.f, xzv = 0.f, xnv = 0.f;
        if (j < NBS*HH) {
            const __half* xr = &xg[((size_t)(b0 + m)*TT + t)*G3];
            xrv = __half2float(xr[jj]);
            xzv = __half2float(xr[HH + jj]);
            xnv = __half2float(xr[2*HH + jj]);
        }
        /* gh[s][j] = sum_k h16[s][k] * Wreg[k] + bh[j]  (b128 LDS broadcast) */
        float a0 = bhj, a1 = bhj;
#pragma unroll
        for (int p = 0; p < NQ/2; ++p) {
            float4 h0raw = *reinterpret_cast<const float4*>(&hshh[0][8*p]);
            float4 h1raw = *reinterpret_cast<const float4*>(&hshh[1][8*p]);
            const __half2* h0 = reinterpret_cast<const __half2*>(&h0raw);
            const __half2* h1 = reinterpret_cast<const __half2*>(&h1raw);
            float2 w0 = wreg[2*p], w1 = wreg[2*p+1];
            const __half2* wA = reinterpret_cast<const __half2*>(&w0);
            const __half2* wB = reinterpret_cast<const __half2*>(&w1);
            a0 = fdot2(h0[0], wA[0], a0); a0 = fdot2(h0[1], wA[1], a0);
            a0 = fdot2(h0[2], wB[0], a0); a0 = fdot2(h0[3], wB[1], a0);
            a1 = fdot2(h1[0], wA[0], a1); a1 = fdot2(h1[1], wA[1], a1);
            a1 = fdot2(h1[2], wB[0], a1); a1 = fdot2(h1[3], wB[1], a1);
        }
        gh[0][j] = a0; gh[1][j] = a1;
        __syncthreads();
        if (j < NBS*HH) {
            int b = b0 + m;
            int L = m ? L1 : L0;
            float gr = sigf(xrv + gh[m][jj]);
            float gz = sigf(xzv + gh[m][HH + jj]);
            float gn = tanhf(xnv + gr*gh[m][2*HH + jj]);
            float hold = hsh[m][jj];
            float hnew = (1.f - gz)*gn + gz*hold;
            if (t < L) {
                hsh[m][jj] = hnew;
                hshh[m][jj] = __float2half(hnew);
                if (!dir) out[((size_t)b*TT + t)*HH + jj] = hnew;
                else      out[((size_t)b*TT + (L-1-t))*HH + jj] = hnew;
            } else if (!dir) {
                out[((size_t)b*TT + t)*HH + jj] = 0.f;
            }
        }
        __syncthreads();
    }
    if (j < NBS*HH) {
        int b = b0 + m;
        int L = m ? L1 : L0;
        h_last[b*2*HH + (dir ? HH : 0) + jj] = hsh[m][jj];
        if (dir) {
            for (int t = L; t < TT; ++t) out[((size_t)b*TT + t)*HH + jj] = 0.f;
        }
    }
}

/* ------- scores[b,t] = tanh([out_f|out_b|dyn] @ W1 + b1) @ W2 + b2, masked
   fp16-dot2: inputs converted to half in LDS, W1 quad-packed (132 quads) ------- */
#define SPB 16
#define SCD 528  /* 2*HH + DYNN */
__global__ __launch_bounds__(256) void k_scores(
    const float* __restrict__ out_f, const float* __restrict__ out_b,
    const float* __restrict__ dyn,   const int* __restrict__ traj,
    const float2* __restrict__ Wq1,  const float* __restrict__ b1,
    const float* __restrict__ W2,    const float* __restrict__ b2,
    float* __restrict__ scores)
{
    __shared__ __align__(16) __half in[SPB][SCD];
    __shared__ float part[4][SPB];
    int r0 = blockIdx.x * SPB;
    int j  = threadIdx.x;
    int lane = j & 63, wid = j >> 6;
#pragma unroll
    for (int m = 0; m < SPB; ++m) {
        int r = r0 + m;
        int b = r >> 7;
        in[m][j]      = __float2half(out_f[(size_t)r*HH + j]);
        in[m][HH + j] = __float2half(out_b[(size_t)r*HH + j]);
        if (j < DYNN) in[m][2*HH + j] = __float2half(dyn[b*DYNN + j]);
    }
    __syncthreads();
    float acc[SPB];
#pragma unroll
    for (int m = 0; m < SPB; ++m) acc[m] = 0.f;
    for (int q = 0; q < SCD/4; ++q) {
        float2 wr = Wq1[(size_t)q*HH + j];
        __half2 w01 = reinterpret_cast<__half2*>(&wr)[0];
        __half2 w23 = reinterpret_cast<__half2*>(&wr)[1];
#pragma unroll
        for (int m = 0; m < SPB; ++m) {
            float2 hraw = *reinterpret_cast<const float2*>(&in[m][4*q]);
            __half2 h01 = reinterpret_cast<__half2*>(&hraw)[0];
            __half2 h23 = reinterpret_cast<__half2*>(&hraw)[1];
            acc[m] = fdot2(h01, w01, acc[m]);
            acc[m] = fdot2(h23, w23, acc[m]);
        }
    }
    float b1j = b1[j], w2j = W2[j];
#pragma unroll
    for (int m = 0; m < SPB; ++m) {
        float s = tanhf(acc[m] + b1j) * w2j;
#pragma unroll
        for (int off = 32; off > 0; off >>= 1) s += __shfl_xor(s, off, 64);
        if (lane == 0) part[wid][m] = s;
    }
    __syncthreads();
    if (j < SPB) {
        int r = r0 + j;
        int b = r >> 7, t = r & 127;
        float s = part[0][j] + part[1][j] + part[2][j] + part[3][j];
        scores[r] = (traj[b*TT + t] != 0) ? (s + b2[0]) : -1e9f;
    }
}

/* ---------------- softmax over T + context = sum(alpha * rnn_out) ---------------- */
__global__ __launch_bounds__(256) void k_context(
    const float* __restrict__ scores, const float* __restrict__ out_f,
    const float* __restrict__ out_b,  float* __restrict__ context)
{
    __shared__ float al[TT];
    __shared__ float red[256];
    int b = blockIdx.x, j = threadIdx.x;
    float s = (j < TT) ? scores[b*TT + j] : -INFINITY;
    red[j] = s; __syncthreads();
    for (int t = 128; t > 0; t >>= 1) { if (j < t) red[j] = fmaxf(red[j], red[j+t]); __syncthreads(); }
    float mx = red[0]; __syncthreads();
    float e = (j < TT) ? expf(s - mx) : 0.f;
    red[j] = e; __syncthreads();
    for (int t = 128; t > 0; t >>= 1) { if (j < t) red[j] += red[j+t]; __syncthreads(); }
    float tot = red[0];
    if (j < TT) al[j] = e / tot;
    __syncthreads();
    float c0 = 0.f, c1 = 0.f;
    for (int t = 0; t < TT; ++t) {
        float a = al[t];
        c0 += a * out_f[((size_t)b*TT + t)*HH + j];
        c1 += a * out_b[((size_t)b*TT + t)*HH + j];
    }
    context[b*2*HH + j]      = c0;
    context[b*2*HH + HH + j] = c1;
}

/* ---------------- LayerNorm + gate + MLP head ---------------- */
__global__ __launch_bounds__(256) void k_head(
    const float* __restrict__ h_last, const float* __restrict__ context,
    const float* __restrict__ dyn,    const float* __restrict__ ln_g,
    const float* __restrict__ ln_b,   const float* __restrict__ gate_W,
    const float* __restrict__ gate_b, const float* __restrict__ fc_W1,
    const float* __restrict__ fc_b1,  const float* __restrict__ fc_W2,
    const float* __restrict__ fc_b2,  float* __restrict__ outp)
{
    __shared__ float gi[1040];   /* [context 512 | rnn_last 512 | dyn 16] */
    __shared__ float fin[SCD];   /* [final 512 | dyn 16] */
    __shared__ float red[256];
    int b = blockIdx.x, j = threadIdx.x;
    float h0 = h_last[b*2*HH + j], h1 = h_last[b*2*HH + HH + j];
    red[j] = h0 + h1; __syncthreads();
    for (int s = 128; s > 0; s >>= 1) { if (j < s) red[j] += red[j+s]; __syncthreads(); }
    float mu = red[0] / 512.f; __syncthreads();
    float d0 = h0 - mu, d1 = h1 - mu;
    red[j] = d0*d0 + d1*d1; __syncthreads();
    for (int s = 128; s > 0; s >>= 1) { if (j < s) red[j] += red[j+s]; __syncthreads(); }
    float inv = rsqrtf(red[0] / 512.f + 1e-5f); __syncthreads();
    gi[2*HH + j]      = d0*inv*ln_g[j]      + ln_b[j];
    gi[2*HH + HH + j] = d1*inv*ln_g[HH + j] + ln_b[HH + j];
    gi[j]      = context[b*2*HH + j];
    gi[HH + j] = context[b*2*HH + HH + j];
    if (j < DYNN) gi[1024 + j] = dyn[b*DYNN + j];
    __syncthreads();
    float a0 = gate_b[j], a1 = gate_b[HH + j];
    for (int k = 0; k < 1040; ++k) {
        float x = gi[k];
        a0 += x * gate_W[k*2*HH + j];
        a1 += x * gate_W[k*2*HH + HH + j];
    }
    float z0 = sigf(a0), z1 = sigf(a1);
    fin[j]      = z0*gi[j]      + (1.f - z0)*gi[2*HH + j];
    fin[HH + j] = z1*gi[HH + j] + (1.f - z1)*gi[2*HH + HH + j];
    if (j < DYNN) fin[2*HH + j] = gi[1024 + j];
    __syncthreads();
    float acc = fc_b1[j];
    for (int k = 0; k < SCD; ++k) acc += fin[k]*fc_W1[k*HH + j];
    float x = acc;
    float hfc = 0.5f * x * (1.f + erff(x * 0.70710678118654752f));  /* exact GELU */
    red[j] = hfc * fc_W2[j]; __syncthreads();
    for (int s = 128; s > 0; s >>= 1) { if (j < s) red[j] += red[j+s]; __syncthreads(); }
    if (j == 0) outp[b] = red[0] + fc_b2[0];
}

extern "C" void kernel_launch(void* const* d_in, const int* in_sizes, int n_in,
                              void* d_out, int out_size, void* d_ws, size_t ws_size,
                              hipStream_t stream)
{
    const float* x0      = (const float*)d_in[0];
    const float* dyn     = (const float*)d_in[1];
    const float* Wproj   = (const float*)d_in[2];
    const float* bproj   = (const float*)d_in[3];
    const float* Wz      = (const float*)d_in[4];
    const float* bz      = (const float*)d_in[5];
    const float* Wr      = (const float*)d_in[6];
    const float* br      = (const float*)d_in[7];
    const float* Wn      = (const float*)d_in[8];
    const float* bn      = (const float*)d_in[9];
    const float* id_emb  = (const float*)d_in[10];
    const float* film_W1 = (const float*)d_in[11];
    const float* film_b1 = (const float*)d_in[12];
    const float* film_W2 = (const float*)d_in[13];
    const float* film_b2 = (const float*)d_in[14];
    const float* gWi_f   = (const float*)d_in[15];
    const float* gWh_f   = (const float*)d_in[16];
    const float* gbi_f   = (const float*)d_in[17];
    const float* gbh_f   = (const float*)d_in[18];
    const float* gWi_b   = (const float*)d_in[19];
    const float* gWh_b   = (const float*)d_in[20];
    const float* gbi_b   = (const float*)d_in[21];
    const float* gbh_b   = (const float*)d_in[22];
    const float* ln_g    = (const float*)d_in[23];
    const float* ln_b    = (const float*)d_in[24];
    const float* attn_W1 = (const float*)d_in[25];
    const float* attn_b1 = (const float*)d_in[26];
    const float* attn_W2 = (const float*)d_in[27];
    const float* attn_b2 = (const float*)d_in[28];
    const float* gate_W  = (const float*)d_in[29];
    const float* gate_b  = (const float*)d_in[30];
    const float* fc_W1   = (const float*)d_in[31];
    const float* fc_b1   = (const float*)d_in[32];
    const float* fc_W2   = (const float*)d_in[33];
    const float* fc_b2   = (const float*)d_in[34];
    const int*   traj    = (const int*)d_in[35];
    const int*   lengths = (const int*)d_in[36];
    const int*   e_src   = (const int*)d_in[37];
    const int*   e_dst   = (const int*)d_in[38];

    float* ws = (float*)d_ws;
    const size_t off_h      = 0;
    const size_t off_hagg   = (size_t)NN*HH;                     /* 12,800,000 */
    const size_t off_xgf    = off_hagg;
    const size_t off_xgb    = off_xgf + (size_t)BB*TT*G3/2;
    const size_t off_outf   = 0;
    const size_t off_outb   = off_xgb + (size_t)BB*TT*G3/2;      /* 37,965,824 */
    const size_t off_film   = off_outb + (size_t)BB*TT*HH;       /* 46,354,432 */
    const size_t off_hlast  = off_film + (size_t)BB*2*HH;
    const size_t off_scores = off_hlast + (size_t)BB*2*HH;
    const size_t off_ctx    = off_scores + (size_t)BB*TT;
    const size_t off_wqf    = off_ctx + (size_t)BB*2*HH;
    const size_t off_wqb    = off_wqf + (size_t)NQ*G3*2;         /* 98,304 floats each */
    const size_t off_wqz    = off_wqb + (size_t)NQ*G3*2;
    const size_t off_wqr    = off_wqz + (size_t)NQG*HH*2;        /* 40,960 floats each */
    const size_t off_wqn    = off_wqr + (size_t)NQG*HH*2;
    const size_t off_wif    = off_wqn + (size_t)NQG*HH*2;        /* 116,736 floats each */
    const size_t off_wib    = off_wif + (size_t)NQX*G3*2;
    const size_t off_wa     = off_wib + (size_t)NQX*G3*2;        /* 67,584 floats */
    const size_t off_h16    = 27000000;                          /* inside dead xg_b region */

    float*   h      = ws + off_h;
    float*   hagg   = ws + off_hagg;
    __half*  xg_f   = (__half*)(ws + off_xgf);
    __half*  xg_b   = (__half*)(ws + off_xgb);
    float*   out_f  = ws + off_outf;
    float*   out_b  = ws + off_outb;
    float*   film   = ws + off_film;
    float*   hlast  = ws + off_hlast;
    float*   scores = ws + off_scores;
    float*   ctx    = ws + off_ctx;
    __half2* wq_f   = (__half2*)(ws + off_wqf);
    __half2* wq_b   = (__half2*)(ws + off_wqb);
    float2*  wqz    = (float2*)(ws + off_wqz);
    float2*  wqr    = (float2*)(ws + off_wqr);
    float2*  wqn    = (float2*)(ws + off_wqn);
    float2*  wqi_f  = (float2*)(ws + off_wif);
    float2*  wqi_b  = (float2*)(ws + off_wib);
    float2*  wqa    = (float2*)(ws + off_wa);
    __half*  h16    = (__half*)(ws + off_h16);

    /* CSR scratch lives after hagg, inside the xg region (dead after GNN) */
    int* cnt  = (int*)(ws + off_hagg + (size_t)NN*HH);  /* [NN]   */
    int* cur  = cnt + NN;                               /* [NN]   */
    int* offs = cur + NN;                               /* [NN+1] */
    int* srcb = offs + NN + 1;                          /* [EE]   */

    /* ---- GNN ---- */
    k_proj<<<(NN + NPB - 1)/NPB, 256, 0, stream>>>(x0, Wproj, bproj, h, h16);

    /* pack weights once per call */
    k_wt2<<<NQ, 768, 0, stream>>>(gWh_f, wq_f);
    k_wt2<<<NQ, 768, 0, stream>>>(gWh_b, wq_b);
    k_wtg<<<NQG, 256, 0, stream>>>(Wz, wqz);
    k_wtg<<<NQG, 256, 0, stream>>>(Wr, wqr);
    k_wtg<<<NQG, 256, 0, stream>>>(Wn, wqn);
    k_wtg<<<SCD/4, 256, 0, stream>>>(attn_W1, wqa);
    k_wti<<<NQX, 768, 0, stream>>>(gWi_f, wqi_f);
    k_wti<<<NQX, 768, 0, stream>>>(gWi_b, wqi_b);

    /* build CSR once per call (graph static across the 3 steps) */
    hipMemsetAsync(cnt, 0, 2*(size_t)NN*sizeof(int), stream);   /* cnt + cur */
    k_hist<<<(EE + 255)/256, 256, 0, stream>>>(e_dst, cnt);
    k_prefix<<<1, 1024, 0, stream>>>(cnt, offs);
    k_fill<<<(EE + 255)/256, 256, 0, stream>>>(e_src, e_dst, offs, cur, srcb);

    for (int step = 0; step < 3; ++step) {
        k_aggregate<<<(NN + APB - 1)/APB, 256, 0, stream>>>(h16, offs, srcb, hagg);
        k_gnn_update<<<(NN + NPB - 1)/NPB, 256, 0, stream>>>(
            x0, hagg, wqz, wqr, wqn, bz, br, bn, h, h16);
    }

    /* ---- FiLM ---- */
    k_film<<<BB, 256, 0, stream>>>(dyn, film_W1, film_b1, film_W2, film_b2, film);

    /* ---- fused xg (both directions, quad-fp16 dot2) ---- */
    k_xg2<<<2*XGBLK, 256, 0, stream>>>(h, id_emb, dyn, film, traj, lengths,
                                       wqi_f, gbi_f, wqi_b, gbi_b, xg_f, xg_b);

    /* ---- fused GRU scan (register weights, dot2 fp16) ---- */
    k_scan2<<<2*SCBLK, 768, 0, stream>>>(xg_f, xg_b, wq_f, gbh_f, wq_b, gbh_b,
                                         lengths, out_f, out_b, hlast);

    /* ---- attention + head ---- */
    k_scores<<<(BB*TT)/SPB, 256, 0, stream>>>(out_f, out_b, dyn, traj,
                                              wqa, attn_b1, attn_W2, attn_b2, scores);
    k_context<<<BB, 256, 0, stream>>>(scores, out_f, out_b, ctx);
    k_head<<<BB, 256, 0, stream>>>(hlast, ctx, dyn, ln_g, ln_b, gate_W, gate_b,
                                   fc_W1, fc_b1, fc_W2, fc_b2, (float*)d_out);
}

// Round 32
// 2191.685 us; speedup vs baseline: 1.2316x; 1.0107x over previous
//
#include <hip/hip_runtime.h>
#include <hip/hip_fp16.h>
#include <cmath>

#define NN   50000
#define EE   800000
#define FF   64
#define HH   256
#define IDD  32
#define DYNN 16
#define BB   256
#define TT   128
#define DIN  304   /* HH + IDD + DYNN */
#define G3   768   /* 3*HH */
#define NQ   (HH/4)        /* 64 scan weight quads  */
#define NQG  ((FF+HH)/4)   /* 80 gnn weight quads   */
#define NQX  (DIN/4)       /* 76 xg weight quads    */

typedef _Float16 h2_t __attribute__((ext_vector_type(2)));
__device__ __forceinline__ float sigf(float x){ return 1.0f/(1.0f+expf(-x)); }
__device__ __forceinline__ float fdot2(__half2 a, __half2 b, float c) {
    return __builtin_amdgcn_fdot2(*reinterpret_cast<h2_t*>(&a),
                                  *reinterpret_cast<h2_t*>(&b), c, false);
}

/* ---------------- h = tanh(x0 @ Wproj + bproj)  (+ fp16 mirror) ---------------- */
#define NPB 16
__global__ __launch_bounds__(256) void k_proj(
    const float* __restrict__ x0, const float* __restrict__ Wproj,
    const float* __restrict__ bproj, float* __restrict__ h,
    __half* __restrict__ h16)
{
    __shared__ float xs[NPB][FF];
    int n0 = blockIdx.x * NPB;
    int j  = threadIdx.x;
    for (int i = j; i < NPB*FF; i += 256) {
        int m = i / FF, k = i % FF;
        int n = n0 + m;
        xs[m][k] = (n < NN) ? x0[n*FF + k] : 0.f;
    }
    __syncthreads();
    float acc[NPB];
#pragma unroll
    for (int m = 0; m < NPB; ++m) acc[m] = 0.f;
    for (int k = 0; k < FF; ++k) {
        float w = Wproj[k*HH + j];
#pragma unroll
        for (int m = 0; m < NPB; ++m) acc[m] += xs[m][k]*w;
    }
    float b = bproj[j];
#pragma unroll
    for (int m = 0; m < NPB; ++m) {
        int n = n0 + m;
        if (n < NN) {
            float v = tanhf(acc[m] + b);
            h[(size_t)n*HH + j] = v;
            h16[(size_t)n*HH + j] = __float2half(v);
        }
    }
}

/* ------- pack Wh (256x768) into quad-fp16: Wq[q*G3+j] = {Wh[4q..4q+3][j]} ------- */
__global__ __launch_bounds__(768) void k_wt2(
    const float* __restrict__ Wh, __half2* __restrict__ Wq)
{
    int q = blockIdx.x;          /* 0..63  */
    int j = threadIdx.x;         /* 0..767 */
    float w0 = Wh[(size_t)(4*q+0)*G3 + j];
    float w1 = Wh[(size_t)(4*q+1)*G3 + j];
    float w2 = Wh[(size_t)(4*q+2)*G3 + j];
    float w3 = Wh[(size_t)(4*q+3)*G3 + j];
    Wq[((size_t)q*G3 + j)*2 + 0] = __floats2half2_rn(w0, w1);
    Wq[((size_t)q*G3 + j)*2 + 1] = __floats2half2_rn(w2, w3);
}

/* ------- pack [R x 256] into quad-fp16: Wq[q*HH+j] = {W[4q..4q+3][j]} ------- */
__global__ __launch_bounds__(256) void k_wtg(
    const float* __restrict__ W, float2* __restrict__ Wq)
{
    int q = blockIdx.x;
    int j = threadIdx.x;         /* 0..255 */
    __half2 a = __floats2half2_rn(W[(size_t)(4*q+0)*HH + j], W[(size_t)(4*q+1)*HH + j]);
    __half2 b = __floats2half2_rn(W[(size_t)(4*q+2)*HH + j], W[(size_t)(4*q+3)*HH + j]);
    float2 o;
    reinterpret_cast<__half2*>(&o)[0] = a;
    reinterpret_cast<__half2*>(&o)[1] = b;
    Wq[(size_t)q*HH + j] = o;
}

/* ------- pack xg Wi (304x768) into quad-fp16: Wq[q*G3+j] = {Wi[4q..4q+3][j]} ------- */
__global__ __launch_bounds__(768) void k_wti(
    const float* __restrict__ Wi, float2* __restrict__ Wq)
{
    int q = blockIdx.x;          /* 0..75  */
    int j = threadIdx.x;         /* 0..767 */
    __half2 a = __floats2half2_rn(Wi[(size_t)(4*q+0)*G3 + j], Wi[(size_t)(4*q+1)*G3 + j]);
    __half2 b = __floats2half2_rn(Wi[(size_t)(4*q+2)*G3 + j], Wi[(size_t)(4*q+3)*G3 + j]);
    float2 o;
    reinterpret_cast<__half2*>(&o)[0] = a;
    reinterpret_cast<__half2*>(&o)[1] = b;
    Wq[(size_t)q*G3 + j] = o;
}

/* ---------------- CSR build: histogram / prefix / fill ---------------- */
__global__ __launch_bounds__(256) void k_hist(
    const int* __restrict__ dst, int* __restrict__ cnt)
{
    int e = blockIdx.x*256 + threadIdx.x;
    if (e < EE) atomicAdd(&cnt[dst[e]], 1);
}

/* shfl-based hierarchical scan: 4 barriers per 1024-chunk (vs 22) */
__global__ __launch_bounds__(1024) void k_prefix(
    const int* __restrict__ cnt, int* __restrict__ offs)
{
    __shared__ int wsum[16];
    __shared__ int carry_s;
    int j = threadIdx.x;
    int wid = j >> 6, lane = j & 63;
    if (j == 0) carry_s = 0;
    __syncthreads();
    for (int base = 0; base < NN; base += 1024) {
        int v = (base + j < NN) ? cnt[base + j] : 0;
        /* inclusive scan within wave */
        int s = v;
#pragma unroll
        for (int d = 1; d < 64; d <<= 1) {
            int t = __shfl_up(s, d, 64);
            if (lane >= d) s += t;
        }
        if (lane == 63) wsum[wid] = s;
        __syncthreads();
        /* wave 0 scans the 16 wave sums (exclusive) */
        if (wid == 0) {
            int ws = (lane < 16) ? wsum[lane] : 0;
            int ss = ws;
#pragma unroll
            for (int d = 1; d < 16; d <<= 1) {
                int t = __shfl_up(ss, d, 64);
                if (lane >= d) ss += t;
            }
            if (lane < 16) wsum[lane] = ss - ws;
        }
        __syncthreads();
        int c = carry_s;
        if (base + j < NN) offs[base + j] = c + wsum[wid] + (s - v);  /* exclusive */
        __syncthreads();
        if (j == 1023) carry_s = c + wsum[15] + s;   /* wsum[15]=sum w0..14, s=wave15 total */
        __syncthreads();
    }
    if (j == 0) offs[NN] = carry_s;
}

__global__ __launch_bounds__(256) void k_fill(
    const int* __restrict__ src, const int* __restrict__ dst,
    const int* __restrict__ offs, int* __restrict__ cur,
    int* __restrict__ srcb)
{
    int e = blockIdx.x*256 + threadIdx.x;
    if (e < EE) {
        int d = dst[e];
        int p = atomicAdd(&cur[d], 1);
        srcb[offs[d] + p] = src[e];
    }
}

/* ------- hagg[n] = sum over incoming edges of h16[src] (fp32 accumulate) ------- */
#define APB 4   /* one wave per node, 4 nodes per block */
__global__ __launch_bounds__(256) void k_aggregate(
    const __half* __restrict__ h16, const int* __restrict__ offs,
    const int* __restrict__ srcb, float* __restrict__ hagg)
{
    int w    = threadIdx.x >> 6;
    int lane = threadIdx.x & 63;
    int n = blockIdx.x * APB + w;
    if (n >= NN) return;
    int e0 = offs[n], e1 = offs[n+1];
    float4 acc = {0.f, 0.f, 0.f, 0.f};
    int e = e0;
    for (; e + 4 <= e1; e += 4) {
        int s0 = srcb[e], s1 = srcb[e+1], s2 = srcb[e+2], s3 = srcb[e+3];
        float2 r0 = *reinterpret_cast<const float2*>(&h16[(size_t)s0*HH + lane*4]);
        float2 r1 = *reinterpret_cast<const float2*>(&h16[(size_t)s1*HH + lane*4]);
        float2 r2 = *reinterpret_cast<const float2*>(&h16[(size_t)s2*HH + lane*4]);
        float2 r3 = *reinterpret_cast<const float2*>(&h16[(size_t)s3*HH + lane*4]);
#pragma unroll
        for (int u = 0; u < 4; ++u) {
            float2* rp = (u==0)?&r0:(u==1)?&r1:(u==2)?&r2:&r3;
            float2 a = __half22float2(reinterpret_cast<__half2*>(rp)[0]);
            float2 b = __half22float2(reinterpret_cast<__half2*>(rp)[1]);
            acc.x += a.x; acc.y += a.y; acc.z += b.x; acc.w += b.y;
        }
    }
    for (; e < e1; ++e) {
        int s = srcb[e];
        float2 r = *reinterpret_cast<const float2*>(&h16[(size_t)s*HH + lane*4]);
        float2 a = __half22float2(reinterpret_cast<__half2*>(&r)[0]);
        float2 b = __half22float2(reinterpret_cast<__half2*>(&r)[1]);
        acc.x += a.x; acc.y += a.y; acc.z += b.x; acc.w += b.y;
    }
    *reinterpret_cast<float4*>(&hagg[(size_t)n*HH + lane*4]) = acc;
}

/* ------- h = (1-zg)*h_agg + zg*tanh([x0, rg*h_agg] @ Wn + bn), dot2-fp16 ------- */
__global__ __launch_bounds__(256) void k_gnn_update(
    const float* __restrict__ x0, const float* __restrict__ hagg,
    const float2* __restrict__ wqz, const float2* __restrict__ wqr,
    const float2* __restrict__ wqn,
    const float* __restrict__ bz, const float* __restrict__ br,
    const float* __restrict__ bn, float* __restrict__ h,
    __half* __restrict__ h16)
{
    __shared__ __align__(16) __half inh[NPB][FF+HH];  /* [x0(64) | hagg(256)] fp16 */
    __shared__ __align__(16) __half rhh[NPB][HH];     /* rg*hagg fp16 */
    __shared__ float hsf[NPB][HH];                    /* hagg fp32 (gate math) */
    int n0 = blockIdx.x * NPB;
    int j  = threadIdx.x;
    for (int i = j; i < NPB*FF; i += 256) {
        int m = i >> 6, k = i & 63;
        int n = n0 + m;
        inh[m][k] = __float2half((n < NN) ? x0[n*FF + k] : 0.f);
    }
#pragma unroll
    for (int m = 0; m < NPB; ++m) {
        int n = n0 + m;
        float hv = (n < NN) ? hagg[(size_t)n*HH + j] : 0.f;
        hsf[m][j] = hv;
        inh[m][FF + j] = __float2half(hv);
    }
    __syncthreads();

    float az[NPB], ar[NPB];
#pragma unroll
    for (int m = 0; m < NPB; ++m) { az[m] = 0.f; ar[m] = 0.f; }
    for (int q = 0; q < NQG; ++q) {
        float2 wzr = wqz[(size_t)q*HH + j];
        float2 wrr = wqr[(size_t)q*HH + j];
        __half2 wz01 = reinterpret_cast<__half2*>(&wzr)[0];
        __half2 wz23 = reinterpret_cast<__half2*>(&wzr)[1];
        __half2 wr01 = reinterpret_cast<__half2*>(&wrr)[0];
        __half2 wr23 = reinterpret_cast<__half2*>(&wrr)[1];
#pragma unroll
        for (int m = 0; m < NPB; ++m) {
            float2 hraw = *reinterpret_cast<const float2*>(&inh[m][4*q]);
            __half2 h01 = reinterpret_cast<__half2*>(&hraw)[0];
            __half2 h23 = reinterpret_cast<__half2*>(&hraw)[1];
            az[m] = fdot2(h01, wz01, az[m]); az[m] = fdot2(h23, wz23, az[m]);
            ar[m] = fdot2(h01, wr01, ar[m]); ar[m] = fdot2(h23, wr23, ar[m]);
        }
    }
    float bzj = bz[j], brj = br[j];
    float zg[NPB];
#pragma unroll
    for (int m = 0; m < NPB; ++m) {
        zg[m] = sigf(az[m] + bzj);
        float rg = sigf(ar[m] + brj);
        rhh[m][j] = __float2half(rg * hsf[m][j]);
    }
    __syncthreads();
    float an[NPB];
#pragma unroll
    for (int m = 0; m < NPB; ++m) an[m] = 0.f;
    /* x0 part: quads 0..15 read inh[m][4q] */
    for (int q = 0; q < FF/4; ++q) {
        float2 wnr = wqn[(size_t)q*HH + j];
        __half2 wn01 = reinterpret_cast<__half2*>(&wnr)[0];
        __half2 wn23 = reinterpret_cast<__half2*>(&wnr)[1];
#pragma unroll
        for (int m = 0; m < NPB; ++m) {
            float2 hraw = *reinterpret_cast<const float2*>(&inh[m][4*q]);
            __half2 h01 = reinterpret_cast<__half2*>(&hraw)[0];
            __half2 h23 = reinterpret_cast<__half2*>(&hraw)[1];
            an[m] = fdot2(h01, wn01, an[m]); an[m] = fdot2(h23, wn23, an[m]);
        }
    }
    /* r*h part: quads 16..79 read rhh[m][4q-64] */
    for (int q = FF/4; q < NQG; ++q) {
        float2 wnr = wqn[(size_t)q*HH + j];
        __half2 wn01 = reinterpret_cast<__half2*>(&wnr)[0];
        __half2 wn23 = reinterpret_cast<__half2*>(&wnr)[1];
#pragma unroll
        for (int m = 0; m < NPB; ++m) {
            float2 hraw = *reinterpret_cast<const float2*>(&rhh[m][4*q - FF]);
            __half2 h01 = reinterpret_cast<__half2*>(&hraw)[0];
            __half2 h23 = reinterpret_cast<__half2*>(&hraw)[1];
            an[m] = fdot2(h01, wn01, an[m]); an[m] = fdot2(h23, wn23, an[m]);
        }
    }
    float bnj = bn[j];
#pragma unroll
    for (int m = 0; m < NPB; ++m) {
        int n = n0 + m;
        if (n < NN) {
            float ht = tanhf(an[m] + bnj);
            float hv = (1.f - zg[m])*hsf[m][j] + zg[m]*ht;
            h[(size_t)n*HH + j] = hv;
            h16[(size_t)n*HH + j] = __float2half(hv);
        }
    }
}

/* ---------------- film = tanh((dyn@W1+b1)@W2+b2) ---------------- */
__global__ __launch_bounds__(256) void k_film(
    const float* __restrict__ dyn, const float* __restrict__ W1,
    const float* __restrict__ b1, const float* __restrict__ W2,
    const float* __restrict__ b2, float* __restrict__ film)
{
    __shared__ float t1[HH];
    __shared__ float ds[DYNN];
    int b = blockIdx.x, j = threadIdx.x;
    if (j < DYNN) ds[j] = dyn[b*DYNN + j];
    __syncthreads();
    float acc = b1[j];
    for (int k = 0; k < DYNN; ++k) acc += ds[k]*W1[k*HH + j];
    t1[j] = acc;                 /* inner layer is LINEAR in the reference */
    __syncthreads();
    float a0 = b2[j], a1 = b2[HH + j];
    for (int k = 0; k < HH; ++k) {
        float t = t1[k];
        a0 += t * W2[k*2*HH + j];
        a1 += t * W2[k*2*HH + HH + j];
    }
    film[b*2*HH + j]      = tanhf(a0);
    film[b*2*HH + HH + j] = tanhf(a1);
}

/* -- fused xg for BOTH directions, quad-fp16 dot2: dir = blockIdx.x / 2048 -- */
#define RPB 16
#define XGBLK ((BB*TT)/RPB)   /* 2048 blocks per direction */
__global__ __launch_bounds__(256) void k_xg2(
    const float* __restrict__ hfin, const float* __restrict__ id_emb,
    const float* __restrict__ dyn,  const float* __restrict__ film,
    const int* __restrict__ traj,   const int* __restrict__ lengths,
    const float2* __restrict__ Wqi_f, const float* __restrict__ bi_f,
    const float2* __restrict__ Wqi_b, const float* __restrict__ bi_b,
    __half* __restrict__ xg_f, __half* __restrict__ xg_b)
{
    __shared__ __align__(16) __half in[RPB][DIN];   /* fp16 inputs, 9728 B */
    int dir = blockIdx.x / XGBLK;          /* 0 = fwd, 1 = bwd */
    int r0  = (blockIdx.x - dir*XGBLK) * RPB;
    const float2* Wq = dir ? Wqi_b : Wqi_f;
    const float* bi = dir ? bi_b : bi_f;
    __half* xg = dir ? xg_b : xg_f;
    int j  = threadIdx.x;
#pragma unroll
    for (int m = 0; m < RPB; ++m) {
        int r = r0 + m;
        int b = r >> 7, t = r & 127;
        int tt = t;
        if (dir) { int L = lengths[b]; tt = L - 1 - t; if (tt < 0) tt = 0; }
        int idx = traj[b*TT + tt];
        float g  = film[b*2*HH + j];
        float bf = film[b*2*HH + HH + j];
        in[m][j] = __float2half(hfin[(size_t)idx*HH + j]*(1.f + g) + bf);
        if (j < IDD)               in[m][HH + j] = __float2half(id_emb[(size_t)idx*IDD + j]);
        else if (j < IDD + DYNN)   in[m][HH + IDD + (j - IDD)] = __float2half(dyn[b*DYNN + (j - IDD)]);
    }
    __syncthreads();
    float a0[RPB], a1[RPB], a2[RPB];
#pragma unroll
    for (int m = 0; m < RPB; ++m) { a0[m] = 0.f; a1[m] = 0.f; a2[m] = 0.f; }
    for (int q = 0; q < NQX; ++q) {
        float2 w0r = Wq[(size_t)q*G3 + j];
        float2 w1r = Wq[(size_t)q*G3 + HH + j];
        float2 w2r = Wq[(size_t)q*G3 + 2*HH + j];
        __half2 w0a = reinterpret_cast<__half2*>(&w0r)[0];
        __half2 w0b = reinterpret_cast<__half2*>(&w0r)[1];
        __half2 w1a = reinterpret_cast<__half2*>(&w1r)[0];
        __half2 w1b = reinterpret_cast<__half2*>(&w1r)[1];
        __half2 w2a = reinterpret_cast<__half2*>(&w2r)[0];
        __half2 w2b = reinterpret_cast<__half2*>(&w2r)[1];
#pragma unroll
        for (int m = 0; m < RPB; ++m) {
            float2 hraw = *reinterpret_cast<const float2*>(&in[m][4*q]);
            __half2 h01 = reinterpret_cast<__half2*>(&hraw)[0];
            __half2 h23 = reinterpret_cast<__half2*>(&hraw)[1];
            a0[m] = fdot2(h01, w0a, a0[m]); a0[m] = fdot2(h23, w0b, a0[m]);
            a1[m] = fdot2(h01, w1a, a1[m]); a1[m] = fdot2(h23, w1b, a1[m]);
            a2[m] = fdot2(h01, w2a, a2[m]); a2[m] = fdot2(h23, w2b, a2[m]);
        }
    }
    float bi0 = bi[j], bi1 = bi[HH + j], bi2 = bi[2*HH + j];
#pragma unroll
    for (int m = 0; m < RPB; ++m) {
        __half* o = &xg[(size_t)(r0 + m)*G3];
        o[j]        = __float2half(a0[m] + bi0);
        o[HH + j]   = __float2half(a1[m] + bi1);
        o[2*HH + j] = __float2half(a2[m] + bi2);
    }
}

/* -- fused masked GRU scan: NBS=2, dot2 fp16 (proven best structure) -- */
#define NBS 2
#define SCBLK (BB/NBS)   /* 128 blocks per direction */
__global__ __launch_bounds__(768, 3) void k_scan2(
    const __half* __restrict__ xg_f, const __half* __restrict__ xg_b,
    const __half2* __restrict__ Wq_f, const float* __restrict__ bh_f,
    const __half2* __restrict__ Wq_b, const float* __restrict__ bh_b,
    const int* __restrict__ lengths,
    float* __restrict__ out_f, float* __restrict__ out_b,
    float* __restrict__ h_last)
{
    __shared__ float hsh[NBS][HH];                 /* fp32 master state   */
    __shared__ __align__(16) __half hshh[NBS][HH]; /* fp16 shadow (matvec)*/
    __shared__ float gh[NBS][G3];                  /* h @ Wh + bh         */
    int dir  = blockIdx.x / SCBLK;          /* 0 = fwd, 1 = bwd */
    int bblk = blockIdx.x - dir*SCBLK;
    const __half* xg = dir ? xg_b : xg_f;
    const __half2* Wq = dir ? Wq_b : Wq_f;
    const float* bh = dir ? bh_b : bh_f;
    float* out = dir ? out_b : out_f;
    int b0 = bblk * NBS;
    int j  = threadIdx.x;            /* 0..767 : output column */
    int m  = j >> 8;                 /* valid when j<512 */
    int jj = j & 255;
    if (j < NBS*HH) { hsh[j >> 8][j & 255] = 0.f; hshh[j >> 8][j & 255] = __float2half(0.f); }
    int L0 = lengths[b0], L1 = lengths[b0 + 1];
    float bhj = bh[j];
    const float2* wqp = reinterpret_cast<const float2*>(Wq) + j;
    float2 wreg[NQ];
#pragma unroll
    for (int q = 0; q < NQ; ++q) wreg[q] = wqp[(size_t)q*G3];
    __syncthreads();
    for (int t = 0; t < TT; ++t) {
        /* prefetch my xg entries for this step (hidden under the matvec) */
        float xrv = 0.f, xzv = 0.f, xnv = 0.f;
        if (j < NBS*HH) {
            const __half* xr = &xg[((size_t)(b0 + m)*TT + t)*G3];
            xrv = __half2float(xr[jj]);
            xzv = __half2float(xr[HH + jj]);
            xnv = __half2float(xr[2*HH + jj]);
        }
        /* gh[s][j] = sum_k h16[s][k] * Wreg[k] + bh[j]  (b128 LDS broadcast) */
        float a0 = bhj, a1 = bhj;
#pragma unroll
        for (int p = 0; p < NQ/2; ++p) {
            float4 h0raw = *reinterpret_cast<const float4*>(&hshh[0][8*p]);
            float4 h1raw = *reinterpret_cast<const float4*>(&hshh[1][8*p]);
            const __half2* h0 = reinterpret_cast<const __half2*>(&h0raw);
            const __half2* h1 = reinterpret_cast<const __half2*>(&h1raw);
            float2 w0 = wreg[2*p], w1 = wreg[2*p+1];
            const __half2* wA = reinterpret_cast<const __half2*>(&w0);
            const __half2* wB = reinterpret_cast<const __half2*>(&w1);
            a0 = fdot2(h0[0], wA[0], a0); a0 = fdot2(h0[1], wA[1], a0);
            a0 = fdot2(h0[2], wB[0], a0); a0 = fdot2(h0[3], wB[1], a0);
            a1 = fdot2(h1[0], wA[0], a1); a1 = fdot2(h1[1], wA[1], a1);
            a1 = fdot2(h1[2], wB[0], a1); a1 = fdot2(h1[3], wB[1], a1);
        }
        gh[0][j] = a0; gh[1][j] = a1;
        __syncthreads();
        if (j < NBS*HH) {
            int b = b0 + m;
            int L = m ? L1 : L0;
            float gr = sigf(xrv + gh[m][jj]);
            float gz = sigf(xzv + gh[m][HH + jj]);
            float gn = tanhf(xnv + gr*gh[m][2*HH + jj]);
            float hold = hsh[m][jj];
            float hnew = (1.f - gz)*gn + gz*hold;
            if (t < L) {
                hsh[m][jj] = hnew;
                hshh[m][jj] = __float2half(hnew);
                if (!dir) out[((size_t)b*TT + t)*HH + jj] = hnew;
                else      out[((size_t)b*TT + (L-1-t))*HH + jj] = hnew;
            } else if (!dir) {
                out[((size_t)b*TT + t)*HH + jj] = 0.f;
            }
        }
        __syncthreads();
    }
    if (j < NBS*HH) {
        int b = b0 + m;
        int L = m ? L1 : L0;
        h_last[b*2*HH + (dir ? HH : 0) + jj] = hsh[m][jj];
        if (dir) {
            for (int t = L; t < TT; ++t) out[((size_t)b*TT + t)*HH + jj] = 0.f;
        }
    }
}

/* ------- scores[b,t] = tanh([out_f|out_b|dyn] @ W1 + b1) @ W2 + b2, masked
   fp16-dot2: inputs converted to half in LDS, W1 quad-packed (132 quads) ------- */
#define SPB 16
#define SCD 528  /* 2*HH + DYNN */
__global__ __launch_bounds__(256) void k_scores(
    const float* __restrict__ out_f, const float* __restrict__ out_b,
    const float* __restrict__ dyn,   const int* __restrict__ traj,
    const float2* __restrict__ Wq1,  const float* __restrict__ b1,
    const float* __restrict__ W2,    const float* __restrict__ b2,
    float* __restrict__ scores)
{
    __shared__ __align__(16) __half in[SPB][SCD];
    __shared__ float part[4][SPB];
    int r0 = blockIdx.x * SPB;
    int j  = threadIdx.x;
    int lane = j & 63, wid = j >> 6;
#pragma unroll
    for (int m = 0; m < SPB; ++m) {
        int r = r0 + m;
        int b = r >> 7;
        in[m][j]      = __float2half(out_f[(size_t)r*HH + j]);
        in[m][HH + j] = __float2half(out_b[(size_t)r*HH + j]);
        if (j < DYNN) in[m][2*HH + j] = __float2half(dyn[b*DYNN + j]);
    }
    __syncthreads();
    float acc[SPB];
#pragma unroll
    for (int m = 0; m < SPB; ++m) acc[m] = 0.f;
    for (int q = 0; q < SCD/4; ++q) {
        float2 wr = Wq1[(size_t)q*HH + j];
        __half2 w01 = reinterpret_cast<__half2*>(&wr)[0];
        __half2 w23 = reinterpret_cast<__half2*>(&wr)[1];
#pragma unroll
        for (int m = 0; m < SPB; ++m) {
            float2 hraw = *reinterpret_cast<const float2*>(&in[m][4*q]);
            __half2 h01 = reinterpret_cast<__half2*>(&hraw)[0];
            __half2 h23 = reinterpret_cast<__half2*>(&hraw)[1];
            acc[m] = fdot2(h01, w01, acc[m]);
            acc[m] = fdot2(h23, w23, acc[m]);
        }
    }
    float b1j = b1[j], w2j = W2[j];
#pragma unroll
    for (int m = 0; m < SPB; ++m) {
        float s = tanhf(acc[m] + b1j) * w2j;
#pragma unroll
        for (int off = 32; off > 0; off >>= 1) s += __shfl_xor(s, off, 64);
        if (lane == 0) part[wid][m] = s;
    }
    __syncthreads();
    if (j < SPB) {
        int r = r0 + j;
        int b = r >> 7, t = r & 127;
        float s = part[0][j] + part[1][j] + part[2][j] + part[3][j];
        scores[r] = (traj[b*TT + t] != 0) ? (s + b2[0]) : -1e9f;
    }
}

/* ---------------- softmax over T + context = sum(alpha * rnn_out) ---------------- */
__global__ __launch_bounds__(256) void k_context(
    const float* __restrict__ scores, const float* __restrict__ out_f,
    const float* __restrict__ out_b,  float* __restrict__ context)
{
    __shared__ float al[TT];
    __shared__ float red[256];
    int b = blockIdx.x, j = threadIdx.x;
    float s = (j < TT) ? scores[b*TT + j] : -INFINITY;
    red[j] = s; __syncthreads();
    for (int t = 128; t > 0; t >>= 1) { if (j < t) red[j] = fmaxf(red[j], red[j+t]); __syncthreads(); }
    float mx = red[0]; __syncthreads();
    float e = (j < TT) ? expf(s - mx) : 0.f;
    red[j] = e; __syncthreads();
    for (int t = 128; t > 0; t >>= 1) { if (j < t) red[j] += red[j+t]; __syncthreads(); }
    float tot = red[0];
    if (j < TT) al[j] = e / tot;
    __syncthreads();
    float c0 = 0.f, c1 = 0.f;
    for (int t = 0; t < TT; ++t) {
        float a = al[t];
        c0 += a * out_f[((size_t)b*TT + t)*HH + j];
        c1 += a * out_b[((size_t)b*TT + t)*HH + j];
    }
    context[b*2*HH + j]      = c0;
    context[b*2*HH + HH + j] = c1;
}

/* ---------------- LayerNorm + gate + MLP head ---------------- */
__global__ __launch_bounds__(256) void k_head(
    const float* __restrict__ h_last, const float* __restrict__ context,
    const float* __restrict__ dyn,    const float* __restrict__ ln_g,
    const float* __restrict__ ln_b,   const float* __restrict__ gate_W,
    const float* __restrict__ gate_b, const float* __restrict__ fc_W1,
    const float* __restrict__ fc_b1,  const float* __restrict__ fc_W2,
    const float* __restrict__ fc_b2,  float* __restrict__ outp)
{
    __shared__ float gi[1040];   /* [context 512 | rnn_last 512 | dyn 16] */
    __shared__ float fin[SCD];   /* [final 512 | dyn 16] */
    __shared__ float red[256];
    int b = blockIdx.x, j = threadIdx.x;
    float h0 = h_last[b*2*HH + j], h1 = h_last[b*2*HH + HH + j];
    red[j] = h0 + h1; __syncthreads();
    for (int s = 128; s > 0; s >>= 1) { if (j < s) red[j] += red[j+s]; __syncthreads(); }
    float mu = red[0] / 512.f; __syncthreads();
    float d0 = h0 - mu, d1 = h1 - mu;
    red[j] = d0*d0 + d1*d1; __syncthreads();
    for (int s = 128; s > 0; s >>= 1) { if (j < s) red[j] += red[j+s]; __syncthreads(); }
    float inv = rsqrtf(red[0] / 512.f + 1e-5f); __syncthreads();
    gi[2*HH + j]      = d0*inv*ln_g[j]      + ln_b[j];
    gi[2*HH + HH + j] = d1*inv*ln_g[HH + j] + ln_b[HH + j];
    gi[j]      = context[b*2*HH + j];
    gi[HH + j] = context[b*2*HH + HH + j];
    if (j < DYNN) gi[1024 + j] = dyn[b*DYNN + j];
    __syncthreads();
    float a0 = gate_b[j], a1 = gate_b[HH + j];
    for (int k = 0; k < 1040; ++k) {
        float x = gi[k];
        a0 += x * gate_W[k*2*HH + j];
        a1 += x * gate_W[k*2*HH + HH + j];
    }
    float z0 = sigf(a0), z1 = sigf(a1);
    fin[j]      = z0*gi[j]      + (1.f - z0)*gi[2*HH + j];
    fin[HH + j] = z1*gi[HH + j] + (1.f - z1)*gi[2*HH + HH + j];
    if (j < DYNN) fin[2*HH + j] = gi[1024 + j];
    __syncthreads();
    float acc = fc_b1[j];
    for (int k = 0; k < SCD; ++k) acc += fin[k]*fc_W1[k*HH + j];
    float x = acc;
    float hfc = 0.5f * x * (1.f + erff(x * 0.70710678118654752f));  /* exact GELU */
    red[j] = hfc * fc_W2[j]; __syncthreads();
    for (int s = 128; s > 0; s >>= 1) { if (j < s) red[j] += red[j+s]; __syncthreads(); }
    if (j == 0) outp[b] = red[0] + fc_b2[0];
}

extern "C" void kernel_launch(void* const* d_in, const int* in_sizes, int n_in,
                              void* d_out, int out_size, void* d_ws, size_t ws_size,
                              hipStream_t stream)
{
    const float* x0      = (const float*)d_in[0];
    const float* dyn     = (const float*)d_in[1];
    const float* Wproj   = (const float*)d_in[2];
    const float* bproj   = (const float*)d_in[3];
    const float* Wz      = (const float*)d_in[4];
    const float* bz      = (const float*)d_in[5];
    const float* Wr      = (const float*)d_in[6];
    const float* br      = (const float*)d_in[7];
    const float* Wn      = (const float*)d_in[8];
    const float* bn      = (const float*)d_in[9];
    const float* id_emb  = (const float*)d_in[10];
    const float* film_W1 = (const float*)d_in[11];
    const float* film_b1 = (const float*)d_in[12];
    const float* film_W2 = (const float*)d_in[13];
    const float* film_b2 = (const float*)d_in[14];
    const float* gWi_f   = (const float*)d_in[15];
    const float* gWh_f   = (const float*)d_in[16];
    const float* gbi_f   = (const float*)d_in[17];
    const float* gbh_f   = (const float*)d_in[18];
    const float* gWi_b   = (const float*)d_in[19];
    const float* gWh_b   = (const float*)d_in[20];
    const float* gbi_b   = (const float*)d_in[21];
    const float* gbh_b   = (const float*)d_in[22];
    const float* ln_g    = (const float*)d_in[23];
    const float* ln_b    = (const float*)d_in[24];
    const float* attn_W1 = (const float*)d_in[25];
    const float* attn_b1 = (const float*)d_in[26];
    const float* attn_W2 = (const float*)d_in[27];
    const float* attn_b2 = (const float*)d_in[28];
    const float* gate_W  = (const float*)d_in[29];
    const float* gate_b  = (const float*)d_in[30];
    const float* fc_W1   = (const float*)d_in[31];
    const float* fc_b1   = (const float*)d_in[32];
    const float* fc_W2   = (const float*)d_in[33];
    const float* fc_b2   = (const float*)d_in[34];
    const int*   traj    = (const int*)d_in[35];
    const int*   lengths = (const int*)d_in[36];
    const int*   e_src   = (const int*)d_in[37];
    const int*   e_dst   = (const int*)d_in[38];

    float* ws = (float*)d_ws;
    const size_t off_h      = 0;
    const size_t off_hagg   = (size_t)NN*HH;                     /* 12,800,000 */
    const size_t off_xgf    = off_hagg;
    const size_t off_xgb    = off_xgf + (size_t)BB*TT*G3/2;
    const size_t off_outf   = 0;
    const size_t off_outb   = off_xgb + (size_t)BB*TT*G3/2;      /* 37,965,824 */
    const size_t off_film   = off_outb + (size_t)BB*TT*HH;       /* 46,354,432 */
    const size_t off_hlast  = off_film + (size_t)BB*2*HH;
    const size_t off_scores = off_hlast + (size_t)BB*2*HH;
    const size_t off_ctx    = off_scores + (size_t)BB*TT;
    const size_t off_wqf    = off_ctx + (size_t)BB*2*HH;
    const size_t off_wqb    = off_wqf + (size_t)NQ*G3*2;         /* 98,304 floats each */
    const size_t off_wqz    = off_wqb + (size_t)NQ*G3*2;
    const size_t off_wqr    = off_wqz + (size_t)NQG*HH*2;        /* 40,960 floats each */
    const size_t off_wqn    = off_wqr + (size_t)NQG*HH*2;
    const size_t off_wif    = off_wqn + (size_t)NQG*HH*2;        /* 116,736 floats each */
    const size_t off_wib    = off_wif + (size_t)NQX*G3*2;
    const size_t off_wa     = off_wib + (size_t)NQX*G3*2;        /* 67,584 floats */
    const size_t off_h16    = 27000000;                          /* inside dead xg_b region */

    float*   h      = ws + off_h;
    float*   hagg   = ws + off_hagg;
    __half*  xg_f   = (__half*)(ws + off_xgf);
    __half*  xg_b   = (__half*)(ws + off_xgb);
    float*   out_f  = ws + off_outf;
    float*   out_b  = ws + off_outb;
    float*   film   = ws + off_film;
    float*   hlast  = ws + off_hlast;
    float*   scores = ws + off_scores;
    float*   ctx    = ws + off_ctx;
    __half2* wq_f   = (__half2*)(ws + off_wqf);
    __half2* wq_b   = (__half2*)(ws + off_wqb);
    float2*  wqz    = (float2*)(ws + off_wqz);
    float2*  wqr    = (float2*)(ws + off_wqr);
    float2*  wqn    = (float2*)(ws + off_wqn);
    float2*  wqi_f  = (float2*)(ws + off_wif);
    float2*  wqi_b  = (float2*)(ws + off_wib);
    float2*  wqa    = (float2*)(ws + off_wa);
    __half*  h16    = (__half*)(ws + off_h16);

    /* CSR scratch lives after hagg, inside the xg region (dead after GNN) */
    int* cnt  = (int*)(ws + off_hagg + (size_t)NN*HH);  /* [NN]   */
    int* cur  = cnt + NN;                               /* [NN]   */
    int* offs = cur + NN;                               /* [NN+1] */
    int* srcb = offs + NN + 1;                          /* [EE]   */

    /* ---- GNN ---- */
    k_proj<<<(NN + NPB - 1)/NPB, 256, 0, stream>>>(x0, Wproj, bproj, h, h16);

    /* pack weights once per call */
    k_wt2<<<NQ, 768, 0, stream>>>(gWh_f, wq_f);
    k_wt2<<<NQ, 768, 0, stream>>>(gWh_b, wq_b);
    k_wtg<<<NQG, 256, 0, stream>>>(Wz, wqz);
    k_wtg<<<NQG, 256, 0, stream>>>(Wr, wqr);
    k_wtg<<<NQG, 256, 0, stream>>>(Wn, wqn);
    k_wtg<<<SCD/4, 256, 0, stream>>>(attn_W1, wqa);
    k_wti<<<NQX, 768, 0, stream>>>(gWi_f, wqi_f);
    k_wti<<<NQX, 768, 0, stream>>>(gWi_b, wqi_b);

    /* build CSR once per call (graph static across the 3 steps) */
    hipMemsetAsync(cnt, 0, 2*(size_t)NN*sizeof(int), stream);   /* cnt + cur */
    k_hist<<<(EE + 255)/256, 256, 0, stream>>>(e_dst, cnt);
    k_prefix<<<1, 1024, 0, stream>>>(cnt, offs);
    k_fill<<<(EE + 255)/256, 256, 0, stream>>>(e_src, e_dst, offs, cur, srcb);

    for (int step = 0; step < 3; ++step) {
        k_aggregate<<<(NN + APB - 1)/APB, 256, 0, stream>>>(h16, offs, srcb, hagg);
        k_gnn_update<<<(NN + NPB - 1)/NPB, 256, 0, stream>>>(
            x0, hagg, wqz, wqr, wqn, bz, br, bn, h, h16);
    }

    /* ---- FiLM ---- */
    k_film<<<BB, 256, 0, stream>>>(dyn, film_W1, film_b1, film_W2, film_b2, film);

    /* ---- fused xg (both directions, quad-fp16 dot2) ---- */
    k_xg2<<<2*XGBLK, 256, 0, stream>>>(h, id_emb, dyn, film, traj, lengths,
                                       wqi_f, gbi_f, wqi_b, gbi_b, xg_f, xg_b);

    /* ---- fused GRU scan (register weights, dot2 fp16) ---- */
    k_scan2<<<2*SCBLK, 768, 0, stream>>>(xg_f, xg_b, wq_f, gbh_f, wq_b, gbh_b,
                                         lengths, out_f, out_b, hlast);

    /* ---- attention + head ---- */
    k_scores<<<(BB*TT)/SPB, 256, 0, stream>>>(out_f, out_b, dyn, traj,
                                              wqa, attn_b1, attn_W2, attn_b2, scores);
    k_context<<<BB, 256, 0, stream>>>(scores, out_f, out_b, ctx);
    k_head<<<BB, 256, 0, stream>>>(hlast, ctx, dyn, ln_g, ln_b, gate_W, gate_b,
                                   fc_W1, fc_b1, fc_W2, fc_b2, (float*)d_out);
}

// Round 33
// 2176.735 us; speedup vs baseline: 1.2401x; 1.0069x over previous
//
#include <hip/hip_runtime.h>
#include <hip/hip_fp16.h>
#include <cmath>

#define NN   50000
#define EE   800000
#define FF   64
#define HH   256
#define IDD  32
#define DYNN 16
#define BB   256
#define TT   128
#define DIN  304   /* HH + IDD + DYNN */
#define G3   768   /* 3*HH */
#define NQ   (HH/4)        /* 64 scan weight quads  */
#define NQG  ((FF+HH)/4)   /* 80 gnn weight quads   */
#define NQX  (DIN/4)       /* 76 xg weight quads    */

typedef _Float16 h2_t __attribute__((ext_vector_type(2)));
__device__ __forceinline__ float sigf(float x){ return 1.0f/(1.0f+expf(-x)); }
__device__ __forceinline__ float fdot2(__half2 a, __half2 b, float c) {
    return __builtin_amdgcn_fdot2(*reinterpret_cast<h2_t*>(&a),
                                  *reinterpret_cast<h2_t*>(&b), c, false);
}

/* ---------------- h = tanh(x0 @ Wproj + bproj)  (+ fp16 mirror) ---------------- */
#define NPB 16
__global__ __launch_bounds__(256) void k_proj(
    const float* __restrict__ x0, const float* __restrict__ Wproj,
    const float* __restrict__ bproj, float* __restrict__ h,
    __half* __restrict__ h16)
{
    __shared__ float xs[NPB][FF];
    int n0 = blockIdx.x * NPB;
    int j  = threadIdx.x;
    for (int i = j; i < NPB*FF; i += 256) {
        int m = i / FF, k = i % FF;
        int n = n0 + m;
        xs[m][k] = (n < NN) ? x0[n*FF + k] : 0.f;
    }
    __syncthreads();
    float acc[NPB];
#pragma unroll
    for (int m = 0; m < NPB; ++m) acc[m] = 0.f;
    for (int k = 0; k < FF; ++k) {
        float w = Wproj[k*HH + j];
#pragma unroll
        for (int m = 0; m < NPB; ++m) acc[m] += xs[m][k]*w;
    }
    float b = bproj[j];
#pragma unroll
    for (int m = 0; m < NPB; ++m) {
        int n = n0 + m;
        if (n < NN) {
            float v = tanhf(acc[m] + b);
            h[(size_t)n*HH + j] = v;
            h16[(size_t)n*HH + j] = __float2half(v);
        }
    }
}

/* ------- pack Wh (256x768) into quad-fp16: Wq[q*G3+j] = {Wh[4q..4q+3][j]} ------- */
__global__ __launch_bounds__(768) void k_wt2(
    const float* __restrict__ Wh, __half2* __restrict__ Wq)
{
    int q = blockIdx.x;          /* 0..63  */
    int j = threadIdx.x;         /* 0..767 */
    float w0 = Wh[(size_t)(4*q+0)*G3 + j];
    float w1 = Wh[(size_t)(4*q+1)*G3 + j];
    float w2 = Wh[(size_t)(4*q+2)*G3 + j];
    float w3 = Wh[(size_t)(4*q+3)*G3 + j];
    Wq[((size_t)q*G3 + j)*2 + 0] = __floats2half2_rn(w0, w1);
    Wq[((size_t)q*G3 + j)*2 + 1] = __floats2half2_rn(w2, w3);
}

/* ------- pack [R x 256] into quad-fp16: Wq[q*HH+j] = {W[4q..4q+3][j]} ------- */
__global__ __launch_bounds__(256) void k_wtg(
    const float* __restrict__ W, float2* __restrict__ Wq)
{
    int q = blockIdx.x;
    int j = threadIdx.x;         /* 0..255 */
    __half2 a = __floats2half2_rn(W[(size_t)(4*q+0)*HH + j], W[(size_t)(4*q+1)*HH + j]);
    __half2 b = __floats2half2_rn(W[(size_t)(4*q+2)*HH + j], W[(size_t)(4*q+3)*HH + j]);
    float2 o;
    reinterpret_cast<__half2*>(&o)[0] = a;
    reinterpret_cast<__half2*>(&o)[1] = b;
    Wq[(size_t)q*HH + j] = o;
}

/* ------- pack xg Wi (304x768) into quad-fp16: Wq[q*G3+j] = {Wi[4q..4q+3][j]} ------- */
__global__ __launch_bounds__(768) void k_wti(
    const float* __restrict__ Wi, float2* __restrict__ Wq)
{
    int q = blockIdx.x;          /* 0..75  */
    int j = threadIdx.x;         /* 0..767 */
    __half2 a = __floats2half2_rn(Wi[(size_t)(4*q+0)*G3 + j], Wi[(size_t)(4*q+1)*G3 + j]);
    __half2 b = __floats2half2_rn(Wi[(size_t)(4*q+2)*G3 + j], Wi[(size_t)(4*q+3)*G3 + j]);
    float2 o;
    reinterpret_cast<__half2*>(&o)[0] = a;
    reinterpret_cast<__half2*>(&o)[1] = b;
    Wq[(size_t)q*G3 + j] = o;
}

/* ---------------- CSR build: histogram / prefix / fill ---------------- */
__global__ __launch_bounds__(256) void k_hist(
    const int* __restrict__ dst, int* __restrict__ cnt)
{
    int e = blockIdx.x*256 + threadIdx.x;
    if (e < EE) atomicAdd(&cnt[dst[e]], 1);
}

/* shfl-based hierarchical scan: 4 barriers per 1024-chunk (vs 22) */
__global__ __launch_bounds__(1024) void k_prefix(
    const int* __restrict__ cnt, int* __restrict__ offs)
{
    __shared__ int wsum[16];
    __shared__ int carry_s;
    int j = threadIdx.x;
    int wid = j >> 6, lane = j & 63;
    if (j == 0) carry_s = 0;
    __syncthreads();
    for (int base = 0; base < NN; base += 1024) {
        int v = (base + j < NN) ? cnt[base + j] : 0;
        /* inclusive scan within wave */
        int s = v;
#pragma unroll
        for (int d = 1; d < 64; d <<= 1) {
            int t = __shfl_up(s, d, 64);
            if (lane >= d) s += t;
        }
        if (lane == 63) wsum[wid] = s;
        __syncthreads();
        /* wave 0 scans the 16 wave sums (exclusive) */
        if (wid == 0) {
            int ws = (lane < 16) ? wsum[lane] : 0;
            int ss = ws;
#pragma unroll
            for (int d = 1; d < 16; d <<= 1) {
                int t = __shfl_up(ss, d, 64);
                if (lane >= d) ss += t;
            }
            if (lane < 16) wsum[lane] = ss - ws;
        }
        __syncthreads();
        int c = carry_s;
        if (base + j < NN) offs[base + j] = c + wsum[wid] + (s - v);  /* exclusive */
        __syncthreads();
        if (j == 1023) carry_s = c + wsum[15] + s;   /* wsum[15]=sum w0..14, s=wave15 total */
        __syncthreads();
    }
    if (j == 0) offs[NN] = carry_s;
}

__global__ __launch_bounds__(256) void k_fill(
    const int* __restrict__ src, const int* __restrict__ dst,
    const int* __restrict__ offs, int* __restrict__ cur,
    int* __restrict__ srcb)
{
    int e = blockIdx.x*256 + threadIdx.x;
    if (e < EE) {
        int d = dst[e];
        int p = atomicAdd(&cur[d], 1);
        srcb[offs[d] + p] = src[e];
    }
}

/* ------- hagg[n] = sum over incoming edges of h16[src] (fp32 accumulate) ------- */
#define APB 4   /* one wave per node, 4 nodes per block */
__global__ __launch_bounds__(256) void k_aggregate(
    const __half* __restrict__ h16, const int* __restrict__ offs,
    const int* __restrict__ srcb, float* __restrict__ hagg)
{
    int w    = threadIdx.x >> 6;
    int lane = threadIdx.x & 63;
    int n = blockIdx.x * APB + w;
    if (n >= NN) return;
    int e0 = offs[n], e1 = offs[n+1];
    float4 acc = {0.f, 0.f, 0.f, 0.f};
    int e = e0;
    for (; e + 4 <= e1; e += 4) {
        int s0 = srcb[e], s1 = srcb[e+1], s2 = srcb[e+2], s3 = srcb[e+3];
        float2 r0 = *reinterpret_cast<const float2*>(&h16[(size_t)s0*HH + lane*4]);
        float2 r1 = *reinterpret_cast<const float2*>(&h16[(size_t)s1*HH + lane*4]);
        float2 r2 = *reinterpret_cast<const float2*>(&h16[(size_t)s2*HH + lane*4]);
        float2 r3 = *reinterpret_cast<const float2*>(&h16[(size_t)s3*HH + lane*4]);
#pragma unroll
        for (int u = 0; u < 4; ++u) {
            float2* rp = (u==0)?&r0:(u==1)?&r1:(u==2)?&r2:&r3;
            float2 a = __half22float2(reinterpret_cast<__half2*>(rp)[0]);
            float2 b = __half22float2(reinterpret_cast<__half2*>(rp)[1]);
            acc.x += a.x; acc.y += a.y; acc.z += b.x; acc.w += b.y;
        }
    }
    for (; e < e1; ++e) {
        int s = srcb[e];
        float2 r = *reinterpret_cast<const float2*>(&h16[(size_t)s*HH + lane*4]);
        float2 a = __half22float2(reinterpret_cast<__half2*>(&r)[0]);
        float2 b = __half22float2(reinterpret_cast<__half2*>(&r)[1]);
        acc.x += a.x; acc.y += a.y; acc.z += b.x; acc.w += b.y;
    }
    *reinterpret_cast<float4*>(&hagg[(size_t)n*HH + lane*4]) = acc;
}

/* ------- h = (1-zg)*h_agg + zg*tanh([x0, rg*h_agg] @ Wn + bn), dot2-fp16 ------- */
__global__ __launch_bounds__(256) void k_gnn_update(
    const float* __restrict__ x0, const float* __restrict__ hagg,
    const float2* __restrict__ wqz, const float2* __restrict__ wqr,
    const float2* __restrict__ wqn,
    const float* __restrict__ bz, const float* __restrict__ br,
    const float* __restrict__ bn, float* __restrict__ h,
    __half* __restrict__ h16)
{
    __shared__ __align__(16) __half inh[NPB][FF+HH];  /* [x0(64) | hagg(256)] fp16 */
    __shared__ __align__(16) __half rhh[NPB][HH];     /* rg*hagg fp16 */
    __shared__ float hsf[NPB][HH];                    /* hagg fp32 (gate math) */
    int n0 = blockIdx.x * NPB;
    int j  = threadIdx.x;
    for (int i = j; i < NPB*FF; i += 256) {
        int m = i >> 6, k = i & 63;
        int n = n0 + m;
        inh[m][k] = __float2half((n < NN) ? x0[n*FF + k] : 0.f);
    }
#pragma unroll
    for (int m = 0; m < NPB; ++m) {
        int n = n0 + m;
        float hv = (n < NN) ? hagg[(size_t)n*HH + j] : 0.f;
        hsf[m][j] = hv;
        inh[m][FF + j] = __float2half(hv);
    }
    __syncthreads();

    float az[NPB], ar[NPB];
#pragma unroll
    for (int m = 0; m < NPB; ++m) { az[m] = 0.f; ar[m] = 0.f; }
    for (int q = 0; q < NQG; ++q) {
        float2 wzr = wqz[(size_t)q*HH + j];
        float2 wrr = wqr[(size_t)q*HH + j];
        __half2 wz01 = reinterpret_cast<__half2*>(&wzr)[0];
        __half2 wz23 = reinterpret_cast<__half2*>(&wzr)[1];
        __half2 wr01 = reinterpret_cast<__half2*>(&wrr)[0];
        __half2 wr23 = reinterpret_cast<__half2*>(&wrr)[1];
#pragma unroll
        for (int m = 0; m < NPB; ++m) {
            float2 hraw = *reinterpret_cast<const float2*>(&inh[m][4*q]);
            __half2 h01 = reinterpret_cast<__half2*>(&hraw)[0];
            __half2 h23 = reinterpret_cast<__half2*>(&hraw)[1];
            az[m] = fdot2(h01, wz01, az[m]); az[m] = fdot2(h23, wz23, az[m]);
            ar[m] = fdot2(h01, wr01, ar[m]); ar[m] = fdot2(h23, wr23, ar[m]);
        }
    }
    float bzj = bz[j], brj = br[j];
    float zg[NPB];
#pragma unroll
    for (int m = 0; m < NPB; ++m) {
        zg[m] = sigf(az[m] + bzj);
        float rg = sigf(ar[m] + brj);
        rhh[m][j] = __float2half(rg * hsf[m][j]);
    }
    __syncthreads();
    float an[NPB];
#pragma unroll
    for (int m = 0; m < NPB; ++m) an[m] = 0.f;
    /* x0 part: quads 0..15 read inh[m][4q] */
    for (int q = 0; q < FF/4; ++q) {
        float2 wnr = wqn[(size_t)q*HH + j];
        __half2 wn01 = reinterpret_cast<__half2*>(&wnr)[0];
        __half2 wn23 = reinterpret_cast<__half2*>(&wnr)[1];
#pragma unroll
        for (int m = 0; m < NPB; ++m) {
            float2 hraw = *reinterpret_cast<const float2*>(&inh[m][4*q]);
            __half2 h01 = reinterpret_cast<__half2*>(&hraw)[0];
            __half2 h23 = reinterpret_cast<__half2*>(&hraw)[1];
            an[m] = fdot2(h01, wn01, an[m]); an[m] = fdot2(h23, wn23, an[m]);
        }
    }
    /* r*h part: quads 16..79 read rhh[m][4q-64] */
    for (int q = FF/4; q < NQG; ++q) {
        float2 wnr = wqn[(size_t)q*HH + j];
        __half2 wn01 = reinterpret_cast<__half2*>(&wnr)[0];
        __half2 wn23 = reinterpret_cast<__half2*>(&wnr)[1];
#pragma unroll
        for (int m = 0; m < NPB; ++m) {
            float2 hraw = *reinterpret_cast<const float2*>(&rhh[m][4*q - FF]);
            __half2 h01 = reinterpret_cast<__half2*>(&hraw)[0];
            __half2 h23 = reinterpret_cast<__half2*>(&hraw)[1];
            an[m] = fdot2(h01, wn01, an[m]); an[m] = fdot2(h23, wn23, an[m]);
        }
    }
    float bnj = bn[j];
#pragma unroll
    for (int m = 0; m < NPB; ++m) {
        int n = n0 + m;
        if (n < NN) {
            float ht = tanhf(an[m] + bnj);
            float hv = (1.f - zg[m])*hsf[m][j] + zg[m]*ht;
            h[(size_t)n*HH + j] = hv;
            h16[(size_t)n*HH + j] = __float2half(hv);
        }
    }
}

/* ---------------- film = tanh((dyn@W1+b1)@W2+b2) ---------------- */
__global__ __launch_bounds__(256) void k_film(
    const float* __restrict__ dyn, const float* __restrict__ W1,
    const float* __restrict__ b1, const float* __restrict__ W2,
    const float* __restrict__ b2, float* __restrict__ film)
{
    __shared__ float t1[HH];
    __shared__ float ds[DYNN];
    int b = blockIdx.x, j = threadIdx.x;
    if (j < DYNN) ds[j] = dyn[b*DYNN + j];
    __syncthreads();
    float acc = b1[j];
    for (int k = 0; k < DYNN; ++k) acc += ds[k]*W1[k*HH + j];
    t1[j] = acc;                 /* inner layer is LINEAR in the reference */
    __syncthreads();
    float a0 = b2[j], a1 = b2[HH + j];
    for (int k = 0; k < HH; ++k) {
        float t = t1[k];
        a0 += t * W2[k*2*HH + j];
        a1 += t * W2[k*2*HH + HH + j];
    }
    film[b*2*HH + j]      = tanhf(a0);
    film[b*2*HH + HH + j] = tanhf(a1);
}

/* -- fused xg for BOTH directions, quad-fp16 dot2, RPB=32 (shared batch b) -- */
#define RPB 32
#define XGBLK ((BB*TT)/RPB)   /* 1024 blocks per direction */
__global__ __launch_bounds__(256, 3) void k_xg2(
    const float* __restrict__ hfin, const float* __restrict__ id_emb,
    const float* __restrict__ dyn,  const float* __restrict__ film,
    const int* __restrict__ traj,   const int* __restrict__ lengths,
    const float2* __restrict__ Wqi_f, const float* __restrict__ bi_f,
    const float2* __restrict__ Wqi_b, const float* __restrict__ bi_b,
    __half* __restrict__ xg_f, __half* __restrict__ xg_b)
{
    __shared__ __align__(16) __half in[RPB][DIN];   /* fp16 inputs, 19456 B */
    int dir = blockIdx.x / XGBLK;          /* 0 = fwd, 1 = bwd */
    int r0  = (blockIdx.x - dir*XGBLK) * RPB;
    const float2* Wq = dir ? Wqi_b : Wqi_f;
    const float* bi = dir ? bi_b : bi_f;
    __half* xg = dir ? xg_b : xg_f;
    int j  = threadIdx.x;
    int b  = r0 >> 7;                      /* all RPB rows share one batch */
    float g  = film[b*2*HH + j];
    float bf = film[b*2*HH + HH + j];
    int L = lengths[b];
#pragma unroll
    for (int m = 0; m < RPB; ++m) {
        int t = (r0 + m) & 127;
        int tt = t;
        if (dir) { tt = L - 1 - t; if (tt < 0) tt = 0; }
        int idx = traj[b*TT + tt];
        in[m][j] = __float2half(hfin[(size_t)idx*HH + j]*(1.f + g) + bf);
        if (j < IDD)               in[m][HH + j] = __float2half(id_emb[(size_t)idx*IDD + j]);
        else if (j < IDD + DYNN)   in[m][HH + IDD + (j - IDD)] = __float2half(dyn[b*DYNN + (j - IDD)]);
    }
    __syncthreads();
    float a0[RPB], a1[RPB], a2[RPB];
#pragma unroll
    for (int m = 0; m < RPB; ++m) { a0[m] = 0.f; a1[m] = 0.f; a2[m] = 0.f; }
    for (int q = 0; q < NQX; ++q) {
        float2 w0r = Wq[(size_t)q*G3 + j];
        float2 w1r = Wq[(size_t)q*G3 + HH + j];
        float2 w2r = Wq[(size_t)q*G3 + 2*HH + j];
        __half2 w0a = reinterpret_cast<__half2*>(&w0r)[0];
        __half2 w0b = reinterpret_cast<__half2*>(&w0r)[1];
        __half2 w1a = reinterpret_cast<__half2*>(&w1r)[0];
        __half2 w1b = reinterpret_cast<__half2*>(&w1r)[1];
        __half2 w2a = reinterpret_cast<__half2*>(&w2r)[0];
        __half2 w2b = reinterpret_cast<__half2*>(&w2r)[1];
#pragma unroll
        for (int m = 0; m < RPB; ++m) {
            float2 hraw = *reinterpret_cast<const float2*>(&in[m][4*q]);
            __half2 h01 = reinterpret_cast<__half2*>(&hraw)[0];
            __half2 h23 = reinterpret_cast<__half2*>(&hraw)[1];
            a0[m] = fdot2(h01, w0a, a0[m]); a0[m] = fdot2(h23, w0b, a0[m]);
            a1[m] = fdot2(h01, w1a, a1[m]); a1[m] = fdot2(h23, w1b, a1[m]);
            a2[m] = fdot2(h01, w2a, a2[m]); a2[m] = fdot2(h23, w2b, a2[m]);
        }
    }
    float bi0 = bi[j], bi1 = bi[HH + j], bi2 = bi[2*HH + j];
#pragma unroll
    for (int m = 0; m < RPB; ++m) {
        __half* o = &xg[(size_t)(r0 + m)*G3];
        o[j]        = __float2half(a0[m] + bi0);
        o[HH + j]   = __float2half(a1[m] + bi1);
        o[2*HH + j] = __float2half(a2[m] + bi2);
    }
}

/* -- fused masked GRU scan: NBS=2, dot2 fp16 (proven best structure) -- */
#define NBS 2
#define SCBLK (BB/NBS)   /* 128 blocks per direction */
__global__ __launch_bounds__(768, 3) void k_scan2(
    const __half* __restrict__ xg_f, const __half* __restrict__ xg_b,
    const __half2* __restrict__ Wq_f, const float* __restrict__ bh_f,
    const __half2* __restrict__ Wq_b, const float* __restrict__ bh_b,
    const int* __restrict__ lengths,
    float* __restrict__ out_f, float* __restrict__ out_b,
    float* __restrict__ h_last)
{
    __shared__ float hsh[NBS][HH];                 /* fp32 master state   */
    __shared__ __align__(16) __half hshh[NBS][HH]; /* fp16 shadow (matvec)*/
    __shared__ float gh[NBS][G3];                  /* h @ Wh + bh         */
    int dir  = blockIdx.x / SCBLK;          /* 0 = fwd, 1 = bwd */
    int bblk = blockIdx.x - dir*SCBLK;
    const __half* xg = dir ? xg_b : xg_f;
    const __half2* Wq = dir ? Wq_b : Wq_f;
    const float* bh = dir ? bh_b : bh_f;
    float* out = dir ? out_b : out_f;
    int b0 = bblk * NBS;
    int j  = threadIdx.x;            /* 0..767 : output column */
    int m  = j >> 8;                 /* valid when j<512 */
    int jj = j & 255;
    if (j < NBS*HH) { hsh[j >> 8][j & 255] = 0.f; hshh[j >> 8][j & 255] = __float2half(0.f); }
    int L0 = lengths[b0], L1 = lengths[b0 + 1];
    float bhj = bh[j];
    const float2* wqp = reinterpret_cast<const float2*>(Wq) + j;
    float2 wreg[NQ];
#pragma unroll
    for (int q = 0; q < NQ; ++q) wreg[q] = wqp[(size_t)q*G3];
    __syncthreads();
    for (int t = 0; t < TT; ++t) {
        /* prefetch my xg entries for this step (hidden under the matvec) */
        float xrv = 0.f, xzv = 0.f, xnv = 0.f;
        if (j < NBS*HH) {
            const __half* xr = &xg[((size_t)(b0 + m)*TT + t)*G3];
            xrv = __half2float(xr[jj]);
            xzv = __half2float(xr[HH + jj]);
            xnv = __half2float(xr[2*HH + jj]);
        }
        /* gh[s][j] = sum_k h16[s][k] * Wreg[k] + bh[j]  (b128 LDS broadcast) */
        float a0 = bhj, a1 = bhj;
#pragma unroll
        for (int p = 0; p < NQ/2; ++p) {
            float4 h0raw = *reinterpret_cast<const float4*>(&hshh[0][8*p]);
            float4 h1raw = *reinterpret_cast<const float4*>(&hshh[1][8*p]);
            const __half2* h0 = reinterpret_cast<const __half2*>(&h0raw);
            const __half2* h1 = reinterpret_cast<const __half2*>(&h1raw);
            float2 w0 = wreg[2*p], w1 = wreg[2*p+1];
            const __half2* wA = reinterpret_cast<const __half2*>(&w0);
            const __half2* wB = reinterpret_cast<const __half2*>(&w1);
            a0 = fdot2(h0[0], wA[0], a0); a0 = fdot2(h0[1], wA[1], a0);
            a0 = fdot2(h0[2], wB[0], a0); a0 = fdot2(h0[3], wB[1], a0);
            a1 = fdot2(h1[0], wA[0], a1); a1 = fdot2(h1[1], wA[1], a1);
            a1 = fdot2(h1[2], wB[0], a1); a1 = fdot2(h1[3], wB[1], a1);
        }
        gh[0][j] = a0; gh[1][j] = a1;
        __syncthreads();
        if (j < NBS*HH) {
            int b = b0 + m;
            int L = m ? L1 : L0;
            float gr = sigf(xrv + gh[m][jj]);
            float gz = sigf(xzv + gh[m][HH + jj]);
            float gn = tanhf(xnv + gr*gh[m][2*HH + jj]);
            float hold = hsh[m][jj];
            float hnew = (1.f - gz)*gn + gz*hold;
            if (t < L) {
                hsh[m][jj] = hnew;
                hshh[m][jj] = __float2half(hnew);
                if (!dir) out[((size_t)b*TT + t)*HH + jj] = hnew;
                else      out[((size_t)b*TT + (L-1-t))*HH + jj] = hnew;
            } else if (!dir) {
                out[((size_t)b*TT + t)*HH + jj] = 0.f;
            }
        }
        __syncthreads();
    }
    if (j < NBS*HH) {
        int b = b0 + m;
        int L = m ? L1 : L0;
        h_last[b*2*HH + (dir ? HH : 0) + jj] = hsh[m][jj];
        if (dir) {
            for (int t = L; t < TT; ++t) out[((size_t)b*TT + t)*HH + jj] = 0.f;
        }
    }
}

/* ------- scores[b,t] = tanh([out_f|out_b|dyn] @ W1 + b1) @ W2 + b2, masked
   fp16-dot2: inputs converted to half in LDS, W1 quad-packed (132 quads) ------- */
#define SPB 16
#define SCD 528  /* 2*HH + DYNN */
__global__ __launch_bounds__(256) void k_scores(
    const float* __restrict__ out_f, const float* __restrict__ out_b,
    const float* __restrict__ dyn,   const int* __restrict__ traj,
    const float2* __restrict__ Wq1,  const float* __restrict__ b1,
    const float* __restrict__ W2,    const float* __restrict__ b2,
    float* __restrict__ scores)
{
    __shared__ __align__(16) __half in[SPB][SCD];
    __shared__ float part[4][SPB];
    int r0 = blockIdx.x * SPB;
    int j  = threadIdx.x;
    int lane = j & 63, wid = j >> 6;
#pragma unroll
    for (int m = 0; m < SPB; ++m) {
        int r = r0 + m;
        int b = r >> 7;
        in[m][j]      = __float2half(out_f[(size_t)r*HH + j]);
        in[m][HH + j] = __float2half(out_b[(size_t)r*HH + j]);
        if (j < DYNN) in[m][2*HH + j] = __float2half(dyn[b*DYNN + j]);
    }
    __syncthreads();
    float acc[SPB];
#pragma unroll
    for (int m = 0; m < SPB; ++m) acc[m] = 0.f;
    for (int q = 0; q < SCD/4; ++q) {
        float2 wr = Wq1[(size_t)q*HH + j];
        __half2 w01 = reinterpret_cast<__half2*>(&wr)[0];
        __half2 w23 = reinterpret_cast<__half2*>(&wr)[1];
#pragma unroll
        for (int m = 0; m < SPB; ++m) {
            float2 hraw = *reinterpret_cast<const float2*>(&in[m][4*q]);
            __half2 h01 = reinterpret_cast<__half2*>(&hraw)[0];
            __half2 h23 = reinterpret_cast<__half2*>(&hraw)[1];
            acc[m] = fdot2(h01, w01, acc[m]);
            acc[m] = fdot2(h23, w23, acc[m]);
        }
    }
    float b1j = b1[j], w2j = W2[j];
#pragma unroll
    for (int m = 0; m < SPB; ++m) {
        float s = tanhf(acc[m] + b1j) * w2j;
#pragma unroll
        for (int off = 32; off > 0; off >>= 1) s += __shfl_xor(s, off, 64);
        if (lane == 0) part[wid][m] = s;
    }
    __syncthreads();
    if (j < SPB) {
        int r = r0 + j;
        int b = r >> 7, t = r & 127;
        float s = part[0][j] + part[1][j] + part[2][j] + part[3][j];
        scores[r] = (traj[b*TT + t] != 0) ? (s + b2[0]) : -1e9f;
    }
}

/* ---------------- softmax over T + context = sum(alpha * rnn_out) ---------------- */
__global__ __launch_bounds__(256) void k_context(
    const float* __restrict__ scores, const float* __restrict__ out_f,
    const float* __restrict__ out_b,  float* __restrict__ context)
{
    __shared__ float al[TT];
    __shared__ float red[256];
    int b = blockIdx.x, j = threadIdx.x;
    float s = (j < TT) ? scores[b*TT + j] : -INFINITY;
    red[j] = s; __syncthreads();
    for (int t = 128; t > 0; t >>= 1) { if (j < t) red[j] = fmaxf(red[j], red[j+t]); __syncthreads(); }
    float mx = red[0]; __syncthreads();
    float e = (j < TT) ? expf(s - mx) : 0.f;
    red[j] = e; __syncthreads();
    for (int t = 128; t > 0; t >>= 1) { if (j < t) red[j] += red[j+t]; __syncthreads(); }
    float tot = red[0];
    if (j < TT) al[j] = e / tot;
    __syncthreads();
    float c0 = 0.f, c1 = 0.f;
    for (int t = 0; t < TT; ++t) {
        float a = al[t];
        c0 += a * out_f[((size_t)b*TT + t)*HH + j];
        c1 += a * out_b[((size_t)b*TT + t)*HH + j];
    }
    context[b*2*HH + j]      = c0;
    context[b*2*HH + HH + j] = c1;
}

/* ---------------- LayerNorm + gate + MLP head ---------------- */
__global__ __launch_bounds__(256) void k_head(
    const float* __restrict__ h_last, const float* __restrict__ context,
    const float* __restrict__ dyn,    const float* __restrict__ ln_g,
    const float* __restrict__ ln_b,   const float* __restrict__ gate_W,
    const float* __restrict__ gate_b, const float* __restrict__ fc_W1,
    const float* __restrict__ fc_b1,  const float* __restrict__ fc_W2,
    const float* __restrict__ fc_b2,  float* __restrict__ outp)
{
    __shared__ float gi[1040];   /* [context 512 | rnn_last 512 | dyn 16] */
    __shared__ float fin[SCD];   /* [final 512 | dyn 16] */
    __shared__ float red[256];
    int b = blockIdx.x, j = threadIdx.x;
    float h0 = h_last[b*2*HH + j], h1 = h_last[b*2*HH + HH + j];
    red[j] = h0 + h1; __syncthreads();
    for (int s = 128; s > 0; s >>= 1) { if (j < s) red[j] += red[j+s]; __syncthreads(); }
    float mu = red[0] / 512.f; __syncthreads();
    float d0 = h0 - mu, d1 = h1 - mu;
    red[j] = d0*d0 + d1*d1; __syncthreads();
    for (int s = 128; s > 0; s >>= 1) { if (j < s) red[j] += red[j+s]; __syncthreads(); }
    float inv = rsqrtf(red[0] / 512.f + 1e-5f); __syncthreads();
    gi[2*HH + j]      = d0*inv*ln_g[j]      + ln_b[j];
    gi[2*HH + HH + j] = d1*inv*ln_g[HH + j] + ln_b[HH + j];
    gi[j]      = context[b*2*HH + j];
    gi[HH + j] = context[b*2*HH + HH + j];
    if (j < DYNN) gi[1024 + j] = dyn[b*DYNN + j];
    __syncthreads();
    float a0 = gate_b[j], a1 = gate_b[HH + j];
    for (int k = 0; k < 1040; ++k) {
        float x = gi[k];
        a0 += x * gate_W[k*2*HH + j];
        a1 += x * gate_W[k*2*HH + HH + j];
    }
    float z0 = sigf(a0), z1 = sigf(a1);
    fin[j]      = z0*gi[j]      + (1.f - z0)*gi[2*HH + j];
    fin[HH + j] = z1*gi[HH + j] + (1.f - z1)*gi[2*HH + HH + j];
    if (j < DYNN) fin[2*HH + j] = gi[1024 + j];
    __syncthreads();
    float acc = fc_b1[j];
    for (int k = 0; k < SCD; ++k) acc += fin[k]*fc_W1[k*HH + j];
    float x = acc;
    float hfc = 0.5f * x * (1.f + erff(x * 0.70710678118654752f));  /* exact GELU */
    red[j] = hfc * fc_W2[j]; __syncthreads();
    for (int s = 128; s > 0; s >>= 1) { if (j < s) red[j] += red[j+s]; __syncthreads(); }
    if (j == 0) outp[b] = red[0] + fc_b2[0];
}

extern "C" void kernel_launch(void* const* d_in, const int* in_sizes, int n_in,
                              void* d_out, int out_size, void* d_ws, size_t ws_size,
                              hipStream_t stream)
{
    const float* x0      = (const float*)d_in[0];
    const float* dyn     = (const float*)d_in[1];
    const float* Wproj   = (const float*)d_in[2];
    const float* bproj   = (const float*)d_in[3];
    const float* Wz      = (const float*)d_in[4];
    const float* bz      = (const float*)d_in[5];
    const float* Wr      = (const float*)d_in[6];
    const float* br      = (const float*)d_in[7];
    const float* Wn      = (const float*)d_in[8];
    const float* bn      = (const float*)d_in[9];
    const float* id_emb  = (const float*)d_in[10];
    const float* film_W1 = (const float*)d_in[11];
    const float* film_b1 = (const float*)d_in[12];
    const float* film_W2 = (const float*)d_in[13];
    const float* film_b2 = (const float*)d_in[14];
    const float* gWi_f   = (const float*)d_in[15];
    const float* gWh_f   = (const float*)d_in[16];
    const float* gbi_f   = (const float*)d_in[17];
    const float* gbh_f   = (const float*)d_in[18];
    const float* gWi_b   = (const float*)d_in[19];
    const float* gWh_b   = (const float*)d_in[20];
    const float* gbi_b   = (const float*)d_in[21];
    const float* gbh_b   = (const float*)d_in[22];
    const float* ln_g    = (const float*)d_in[23];
    const float* ln_b    = (const float*)d_in[24];
    const float* attn_W1 = (const float*)d_in[25];
    const float* attn_b1 = (const float*)d_in[26];
    const float* attn_W2 = (const float*)d_in[27];
    const float* attn_b2 = (const float*)d_in[28];
    const float* gate_W  = (const float*)d_in[29];
    const float* gate_b  = (const float*)d_in[30];
    const float* fc_W1   = (const float*)d_in[31];
    const float* fc_b1   = (const float*)d_in[32];
    const float* fc_W2   = (const float*)d_in[33];
    const float* fc_b2   = (const float*)d_in[34];
    const int*   traj    = (const int*)d_in[35];
    const int*   lengths = (const int*)d_in[36];
    const int*   e_src   = (const int*)d_in[37];
    const int*   e_dst   = (const int*)d_in[38];

    float* ws = (float*)d_ws;
    const size_t off_h      = 0;
    const size_t off_hagg   = (size_t)NN*HH;                     /* 12,800,000 */
    const size_t off_xgf    = off_hagg;
    const size_t off_xgb    = off_xgf + (size_t)BB*TT*G3/2;
    const size_t off_outf   = 0;
    const size_t off_outb   = off_xgb + (size_t)BB*TT*G3/2;      /* 37,965,824 */
    const size_t off_film   = off_outb + (size_t)BB*TT*HH;       /* 46,354,432 */
    const size_t off_hlast  = off_film + (size_t)BB*2*HH;
    const size_t off_scores = off_hlast + (size_t)BB*2*HH;
    const size_t off_ctx    = off_scores + (size_t)BB*TT;
    const size_t off_wqf    = off_ctx + (size_t)BB*2*HH;
    const size_t off_wqb    = off_wqf + (size_t)NQ*G3*2;         /* 98,304 floats each */
    const size_t off_wqz    = off_wqb + (size_t)NQ*G3*2;
    const size_t off_wqr    = off_wqz + (size_t)NQG*HH*2;        /* 40,960 floats each */
    const size_t off_wqn    = off_wqr + (size_t)NQG*HH*2;
    const size_t off_wif    = off_wqn + (size_t)NQG*HH*2;        /* 116,736 floats each */
    const size_t off_wib    = off_wif + (size_t)NQX*G3*2;
    const size_t off_wa     = off_wib + (size_t)NQX*G3*2;        /* 67,584 floats */
    const size_t off_h16    = 27000000;                          /* inside dead xg_b region */

    float*   h      = ws + off_h;
    float*   hagg   = ws + off_hagg;
    __half*  xg_f   = (__half*)(ws + off_xgf);
    __half*  xg_b   = (__half*)(ws + off_xgb);
    float*   out_f  = ws + off_outf;
    float*   out_b  = ws + off_outb;
    float*   film   = ws + off_film;
    float*   hlast  = ws + off_hlast;
    float*   scores = ws + off_scores;
    float*   ctx    = ws + off_ctx;
    __half2* wq_f   = (__half2*)(ws + off_wqf);
    __half2* wq_b   = (__half2*)(ws + off_wqb);
    float2*  wqz    = (float2*)(ws + off_wqz);
    float2*  wqr    = (float2*)(ws + off_wqr);
    float2*  wqn    = (float2*)(ws + off_wqn);
    float2*  wqi_f  = (float2*)(ws + off_wif);
    float2*  wqi_b  = (float2*)(ws + off_wib);
    float2*  wqa    = (float2*)(ws + off_wa);
    __half*  h16    = (__half*)(ws + off_h16);

    /* CSR scratch lives after hagg, inside the xg region (dead after GNN) */
    int* cnt  = (int*)(ws + off_hagg + (size_t)NN*HH);  /* [NN]   */
    int* cur  = cnt + NN;                               /* [NN]   */
    int* offs = cur + NN;                               /* [NN+1] */
    int* srcb = offs + NN + 1;                          /* [EE]   */

    /* ---- GNN ---- */
    k_proj<<<(NN + NPB - 1)/NPB, 256, 0, stream>>>(x0, Wproj, bproj, h, h16);

    /* pack weights once per call */
    k_wt2<<<NQ, 768, 0, stream>>>(gWh_f, wq_f);
    k_wt2<<<NQ, 768, 0, stream>>>(gWh_b, wq_b);
    k_wtg<<<NQG, 256, 0, stream>>>(Wz, wqz);
    k_wtg<<<NQG, 256, 0, stream>>>(Wr, wqr);
    k_wtg<<<NQG, 256, 0, stream>>>(Wn, wqn);
    k_wtg<<<SCD/4, 256, 0, stream>>>(attn_W1, wqa);
    k_wti<<<NQX, 768, 0, stream>>>(gWi_f, wqi_f);
    k_wti<<<NQX, 768, 0, stream>>>(gWi_b, wqi_b);

    /* build CSR once per call (graph static across the 3 steps) */
    hipMemsetAsync(cnt, 0, 2*(size_t)NN*sizeof(int), stream);   /* cnt + cur */
    k_hist<<<(EE + 255)/256, 256, 0, stream>>>(e_dst, cnt);
    k_prefix<<<1, 1024, 0, stream>>>(cnt, offs);
    k_fill<<<(EE + 255)/256, 256, 0, stream>>>(e_src, e_dst, offs, cur, srcb);

    for (int step = 0; step < 3; ++step) {
        k_aggregate<<<(NN + APB - 1)/APB, 256, 0, stream>>>(h16, offs, srcb, hagg);
        k_gnn_update<<<(NN + NPB - 1)/NPB, 256, 0, stream>>>(
            x0, hagg, wqz, wqr, wqn, bz, br, bn, h, h16);
    }

    /* ---- FiLM ---- */
    k_film<<<BB, 256, 0, stream>>>(dyn, film_W1, film_b1, film_W2, film_b2, film);

    /* ---- fused xg (both directions, quad-fp16 dot2, RPB=32) ---- */
    k_xg2<<<2*XGBLK, 256, 0, stream>>>(h, id_emb, dyn, film, traj, lengths,
                                       wqi_f, gbi_f, wqi_b, gbi_b, xg_f, xg_b);

    /* ---- fused GRU scan (register weights, dot2 fp16) ---- */
    k_scan2<<<2*SCBLK, 768, 0, stream>>>(xg_f, xg_b, wq_f, gbh_f, wq_b, gbh_b,
                                         lengths, out_f, out_b, hlast);

    /* ---- attention + head ---- */
    k_scores<<<(BB*TT)/SPB, 256, 0, stream>>>(out_f, out_b, dyn, traj,
                                              wqa, attn_b1, attn_W2, attn_b2, scores);
    k_context<<<BB, 256, 0, stream>>>(scores, out_f, out_b, ctx);
    k_head<<<BB, 256, 0, stream>>>(hlast, ctx, dyn, ln_g, ln_b, gate_W, gate_b,
                                   fc_W1, fc_b1, fc_W2, fc_b2, (float*)d_out);
}